// Round 8
// baseline (242.460 us; speedup 1.0000x reference)
//
#include <hip/hip_runtime.h>
#include <hip/hip_fp16.h>
#include <math.h>

// GCN: 2x GraphConv(norm='both') + projection + softmax.
// N=100000 nodes, E=1600000 edges, feats 128 -> 64 -> 64 -> 8. All fp32 I/O.
//
// R20 = R19 resubmitted (previous round failed on container infra, not the
// kernel). R19 (on R18 = 241.9us): gather was VALU-issue bound; ~36% of
// inner-loop issue slots were tail predication (2 v_cmp + 8 v_cndmask per
// k-iter to zero out-of-degree slots). Sentinel ZERO ROW: h gets row NODES
// = all zeros (written by the GEMM epilogues' previously-discarded
// out-of-range lanes; grid already covers rows 100000..100031). Strip-mine
// default pe = NODES -> tail slots load the zero row -> contribute exactly
// 0. All per-slot compares/cndmask deleted; H-row loads unconditional.
// Bit-identical numerics. Everything else frozen at R18.

#define NODES   100000
#define INF     128
#define HID     64
#define NLAB    8

#define SB      512                         // nodes per src super-bucket
#define NSB     ((NODES + SB - 1) / SB)     // 196 (src side)
#define NHALF   ((NODES + 255) / 256)       // 391 dst half-buckets (256 nodes)
#define SCAP    9000                        // per-sb src cap
#define CAPH    4600                        // per-half edge cap (mean 4096, sigma~64)
#define PCHUNK  8192                        // edges per part WG (196 blocks)
#define PEPT    (PCHUNK / 256)              // 32
#define SRCMASK 0x1FFFF                     // 17 bits
#define GSTRIDE 16                          // ints; one gcur counter per 64B line

#define WCVT_ELEMS (64 * (INF + 8) + 64 * (HID + 8))
#define WCVT_WGS   ((WCVT_ELEMS + 255) / 256)

union H8 { int4 i4; __half2 h2[4]; unsigned int u[4]; };
union H2U { __half2 h; unsigned int u; };

typedef _Float16 half8 __attribute__((ext_vector_type(8)));
typedef float floatx4 __attribute__((ext_vector_type(4)));

// acc0 += (float)lo16(h2); acc1 += (float)hi16(h2) — one VOP3P mix-FMA each.
// Exact f16->f32 convert inside the FMA: bit-identical to cvt+add.
__device__ __forceinline__ void fma_mix2(float& a0, float& a1, unsigned int h2) {
    asm("v_fma_mix_f32 %0, %2, 1.0, %0 op_sel_hi:[1,0,0]\n\t"
        "v_fma_mix_f32 %1, %2, 1.0, %1 op_sel:[1,0,0] op_sel_hi:[1,0,0]"
        : "+v"(a0), "+v"(a1) : "v"(h2));
}

// ---------------- build1: partition edges by dst>>8; src vals by src>>9 ----------------
// (+ W convert in trailing blocks)

__global__ void build1_kernel(const int* __restrict__ src, const int* __restrict__ dst,
                              int* __restrict__ gcur_d, int* __restrict__ gcur_s,
                              int* __restrict__ dreg, unsigned short* __restrict__ sreg,
                              int E, int partWGs,
                              const float* __restrict__ W1, const float* __restrict__ W2,
                              _Float16* __restrict__ wt1, _Float16* __restrict__ wt2) {
    __shared__ int hd[NHALF], bd[NHALF], hs[NSB], bs[NSB];
    const int tid = threadIdx.x;

    if (blockIdx.x >= partWGs) {
        // ---- W convert: fp32 [K][64] -> fp16 transposed [64][K+8] ----
        const int N1 = 64 * (INF + 8);
        const int N2 = 64 * (HID + 8);
        int i = (blockIdx.x - partWGs) * 256 + tid;
        if (i < N1) {
            int n = i / (INF + 8), k = i % (INF + 8);
            wt1[i] = (k < INF) ? (_Float16)W1[k * 64 + n] : (_Float16)0.f;
        } else if (i < N1 + N2) {
            int j = i - N1;
            int n = j / (HID + 8), k = j % (HID + 8);
            wt2[j] = (k < HID) ? (_Float16)W2[k * 64 + n] : (_Float16)0.f;
        }
        return;
    }

    const int e0 = blockIdx.x * PCHUNK;

    for (int i = tid; i < NHALF; i += 256) { hd[i] = 0; }
    for (int i = tid; i < NSB; i += 256) { hs[i] = 0; }
    __syncthreads();

    // phase A: LDS histograms (edges re-read from L2 in phase C)
    int es[PEPT], ed[PEPT];
#pragma unroll
    for (int i = 0; i < PEPT; ++i) {
        int e = e0 + tid + i * 256;
        if (e < E) {
            es[i] = src[e]; ed[i] = dst[e];
            atomicAdd(&hd[ed[i] >> 8], 1);
            atomicAdd(&hs[es[i] >> 9], 1);
        } else es[i] = -1;
    }
    __syncthreads();

    // phase B: reserve contiguous runs (chain depth = 196 blocks;
    // line-spread counters -> 587 chains drain in parallel)
    for (int b = tid; b < NHALF; b += 256) {
        int c = hd[b]; bd[b] = c ? atomicAdd(&gcur_d[b * GSTRIDE], c) : 0;
    }
    for (int b = tid; b < NSB; b += 256) {
        int c = hs[b]; bs[b] = c ? atomicAdd(&gcur_s[b * GSTRIDE], c) : 0;
    }
    __syncthreads();
    for (int b = tid; b < NHALF; b += 256) hd[b] = 0;
    for (int b = tid; b < NSB; b += 256) hs[b] = 0;
    __syncthreads();

    // phase C: scatter into runs (dst_local(8b)<<17 | src; src_local as ushort)
#pragma unroll
    for (int i = 0; i < PEPT; ++i) {
        if (es[i] >= 0) {
            int s = es[i], d = ed[i];
            int kb = d >> 8;
            int pos = bd[kb] + atomicAdd(&hd[kb], 1);
            if (pos < CAPH) dreg[(size_t)kb * CAPH + pos] = ((d & 255) << 17) | s;
            int ks = s >> 9;
            int ps = bs[ks] + atomicAdd(&hs[ks], 1);
            if (ps < SCAP) sreg[(size_t)ks * SCAP + ps] = (unsigned short)(s & (SB - 1));
        }
    }
}

// ---------------- src-degree histogram per super-bucket -> norm_s ----------------

__global__ void shist_kernel(const unsigned short* __restrict__ sreg,
                             const int* __restrict__ gcur_s,
                             float* __restrict__ norm_s, int Nn) {
    __shared__ int hist[SB];
    const int tid = threadIdx.x;
    const int sb = blockIdx.x;
    for (int i = tid; i < SB; i += 256) hist[i] = 0;
    __syncthreads();
    const int cnt = min(gcur_s[sb * GSTRIDE], SCAP);
    const unsigned short* base = sreg + (size_t)sb * SCAP;
    for (int i = tid; i < cnt; i += 256) atomicAdd(&hist[base[i]], 1);
    __syncthreads();
    for (int t = tid; t < SB; t += 256) {
        int node = sb * SB + t;
        if (node < Nn) norm_s[node] = rsqrtf(fmaxf((float)hist[t], 1.0f));
    }
}

// ---------------- build2: csr2 (first NHALF blocks) || gemm1 MFMA (rest) ----------------
// csr2: per-half-bucket counting sort (own edges only, wave-scan) -> exact
// CSR + norm_d. gemm1: Hh = fp16( norm_s * (X@W1) ); row Nn (sentinel) = 0.
// Independent (dreg aliases x, not h).

__global__ void build2_kernel(const int* __restrict__ dreg, const int* __restrict__ gcur_d,
                              int* __restrict__ csr, int* __restrict__ starts,
                              int* __restrict__ ends, float* __restrict__ norm_d,
                              const float* __restrict__ Xv, const float* __restrict__ norm,
                              const _Float16* __restrict__ Wt, __half* __restrict__ Hh,
                              int Nn) {
    __shared__ union SMem {
        struct CS { int hist[256]; int cur[256]; int wsum[4]; int sorted[CAPH]; } c;
        _Float16 w[64 * (INF + 8)];
    } sm;
    const int tid = threadIdx.x;

    if (blockIdx.x < NHALF) {
        // ---- csr2: WG j owns nodes [j*256, j*256+256) = dst bucket j ----
        const int j = blockIdx.x;
        const int cnt = min(gcur_d[j * GSTRIDE], CAPH);
        const int* reg = dreg + (size_t)j * CAPH;

        sm.c.hist[tid] = 0;
        __syncthreads();

        for (int i = tid; i < cnt; i += 256)
            atomicAdd(&sm.c.hist[(reg[i] >> 17) & 255], 1);
        __syncthreads();

        // exclusive scan over 256: wave shfl_up scan + 4-word combine
        const int lane = tid & 63, wid = tid >> 6;
        int deg_n = sm.c.hist[tid];
        int v = deg_n;
#pragma unroll
        for (int off = 1; off < 64; off <<= 1) {
            int u = __shfl_up(v, off, 64);
            if (lane >= off) v += u;
        }
        if (lane == 63) sm.c.wsum[wid] = v;
        __syncthreads();
        int wadd = 0;
#pragma unroll
        for (int q = 0; q < 3; ++q) wadd += (q < wid) ? sm.c.wsum[q] : 0;
        int st = v + wadd - deg_n;

        int node = j * 256 + tid;
        if (node < Nn) {
            int gs = j * CAPH + st;
            int dcl = min(deg_n, max(CAPH - st, 0));
            starts[node] = gs;
            ends[node]   = gs + dcl;
            norm_d[node] = rsqrtf(fmaxf((float)deg_n, 1.0f));
        }
        sm.c.cur[tid] = st;
        __syncthreads();

        for (int i = tid; i < cnt; i += 256) {
            int pe = reg[i];
            int pos = atomicAdd(&sm.c.cur[(pe >> 17) & 255], 1);
            if (pos < CAPH) sm.c.sorted[pos] = pe & SRCMASK;
        }
        __syncthreads();

        for (int i = tid; i < cnt; i += 256) csr[(size_t)j * CAPH + i] = sm.c.sorted[i];
        return;
    }

    // ---- gemm1: block = 64 rows, 4 waves x 16; K=128 fp32 input ----
    constexpr int K = INF;
    constexpr int KP = K + 8;
    const int bid = blockIdx.x - NHALF;

    constexpr int NI4 = 64 * KP * 2 / 16;
    for (int i = tid; i < NI4; i += 256)
        ((int4*)sm.w)[i] = ((const int4*)Wt)[i];
    __syncthreads();

    const int w = tid >> 6, lane = tid & 63;
    const int m16 = lane & 15, quad = lane >> 4;
    const int rowA = bid * 64 + w * 16 + m16;
    const int rowC = (rowA < Nn) ? rowA : (Nn - 1);

    floatx4 acc0 = {0.f, 0.f, 0.f, 0.f};
    floatx4 acc1 = acc0, acc2 = acc0, acc3 = acc0;

#pragma unroll
    for (int c = 0; c < K / 32; ++c) {
        const int k0 = c * 32 + quad * 8;
        const float* xrow = Xv + (size_t)rowC * K;
        float4 xa = *(const float4*)(xrow + k0);
        float4 xb = *(const float4*)(xrow + k0 + 4);
        half8 a;
        a[0] = (_Float16)xa.x; a[1] = (_Float16)xa.y;
        a[2] = (_Float16)xa.z; a[3] = (_Float16)xa.w;
        a[4] = (_Float16)xb.x; a[5] = (_Float16)xb.y;
        a[6] = (_Float16)xb.z; a[7] = (_Float16)xb.w;
        half8 b0 = *(const half8*)&sm.w[(0 * 16 + m16) * KP + k0];
        half8 b1 = *(const half8*)&sm.w[(1 * 16 + m16) * KP + k0];
        half8 b2 = *(const half8*)&sm.w[(2 * 16 + m16) * KP + k0];
        half8 b3 = *(const half8*)&sm.w[(3 * 16 + m16) * KP + k0];
        acc0 = __builtin_amdgcn_mfma_f32_16x16x32_f16(a, b0, acc0, 0, 0, 0);
        acc1 = __builtin_amdgcn_mfma_f32_16x16x32_f16(a, b1, acc1, 0, 0, 0);
        acc2 = __builtin_amdgcn_mfma_f32_16x16x32_f16(a, b2, acc2, 0, 0, 0);
        acc3 = __builtin_amdgcn_mfma_f32_16x16x32_f16(a, b3, acc3, 0, 0, 0);
    }

    const int rbase = bid * 64 + w * 16 + quad * 4;
    floatx4 accs[4] = {acc0, acc1, acc2, acc3};
#pragma unroll
    for (int i = 0; i < 4; ++i) {
        int grow = rbase + i;
        if (grow < Nn) {
            float nm = norm[grow];
            __half* o = Hh + (size_t)grow * 64 + m16;
#pragma unroll
            for (int t = 0; t < 4; ++t)
                o[16 * t] = (__half)(accs[t][i] * nm);
        } else if (grow == Nn) {               // sentinel zero row for gather
            __half* o = Hh + (size_t)grow * 64 + m16;
#pragma unroll
            for (int t = 0; t < 4; ++t)
                o[16 * t] = (__half)0.f;
        }
    }
}

// ---------------- standalone MFMA GEMM (layer 2: K=64, fp16 input) ----------------

template <int K, bool IN16>
__global__ void gemm_mfma_kernel(const void* __restrict__ Xv, const float* __restrict__ norm,
                                 const _Float16* __restrict__ Wt, __half* __restrict__ Hh,
                                 int M) {
    constexpr int KP = K + 8;
    __shared__ _Float16 sWt[64 * KP];

    const int tid = threadIdx.x;
    constexpr int NI4 = 64 * KP * 2 / 16;
    for (int i = tid; i < NI4; i += 256)
        ((int4*)sWt)[i] = ((const int4*)Wt)[i];
    __syncthreads();

    const int w = tid >> 6, lane = tid & 63;
    const int m16 = lane & 15, quad = lane >> 4;
    const int rowA = blockIdx.x * 64 + w * 16 + m16;
    const int rowC = (rowA < M) ? rowA : (M - 1);

    floatx4 acc0 = {0.f, 0.f, 0.f, 0.f};
    floatx4 acc1 = acc0, acc2 = acc0, acc3 = acc0;

#pragma unroll
    for (int c = 0; c < K / 32; ++c) {
        const int k0 = c * 32 + quad * 8;
        half8 a;
        if constexpr (IN16) {
            const _Float16* xrow = (const _Float16*)Xv + (size_t)rowC * K;
            a = *(const half8*)(xrow + k0);
        } else {
            const float* xrow = (const float*)Xv + (size_t)rowC * K;
            float4 xa = *(const float4*)(xrow + k0);
            float4 xb = *(const float4*)(xrow + k0 + 4);
            a[0] = (_Float16)xa.x; a[1] = (_Float16)xa.y;
            a[2] = (_Float16)xa.z; a[3] = (_Float16)xa.w;
            a[4] = (_Float16)xb.x; a[5] = (_Float16)xb.y;
            a[6] = (_Float16)xb.z; a[7] = (_Float16)xb.w;
        }
        half8 b0 = *(const half8*)&sWt[(0 * 16 + m16) * KP + k0];
        half8 b1 = *(const half8*)&sWt[(1 * 16 + m16) * KP + k0];
        half8 b2 = *(const half8*)&sWt[(2 * 16 + m16) * KP + k0];
        half8 b3 = *(const half8*)&sWt[(3 * 16 + m16) * KP + k0];
        acc0 = __builtin_amdgcn_mfma_f32_16x16x32_f16(a, b0, acc0, 0, 0, 0);
        acc1 = __builtin_amdgcn_mfma_f32_16x16x32_f16(a, b1, acc1, 0, 0, 0);
        acc2 = __builtin_amdgcn_mfma_f32_16x16x32_f16(a, b2, acc2, 0, 0, 0);
        acc3 = __builtin_amdgcn_mfma_f32_16x16x32_f16(a, b3, acc3, 0, 0, 0);
    }

    const int rbase = blockIdx.x * 64 + w * 16 + quad * 4;
    floatx4 accs[4] = {acc0, acc1, acc2, acc3};
#pragma unroll
    for (int i = 0; i < 4; ++i) {
        int grow = rbase + i;
        if (grow < M) {
            float nm = norm[grow];
            __half* o = Hh + (size_t)grow * 64 + m16;
#pragma unroll
            for (int t = 0; t < 4; ++t)
                o[16 * t] = (__half)(accs[t][i] * nm);
        } else if (grow == M) {                // sentinel zero row for gather
            __half* o = Hh + (size_t)grow * 64 + m16;
#pragma unroll
            for (int t = 0; t < 4; ++t)
                o[16 * t] = (__half)0.f;
        }
    }
}

// ---------------- pull gather: 2 nodes per wave, pk_f16 pair-combine ----------------
// Wave = 2 x 32-lane halves, one node each; 4 edge-slot groups x 8 col-chunks
// per half. Wave-uniform trips (dmax over halves) keep shuffles at full exec.
// SENTINEL: tail slots get pe = Nn -> load h's zero row -> contribute exactly
// 0; all per-slot compares/cndmask removed, loads unconditional.
// Accumulate: pair hadd2 (v_pk_add_f16) then v_fma_mix_f32 per feature.
// PROJ=false: epilogue writes fp16 row to Xh. PROJ=true (layer 2): fused
// x@Wp + bp + softmax (labels 2/g-group, LDS Wp transposed pad-65,
// butterflies over c then g; c==0 lanes store float2).

template <bool PROJ>
__global__ void gather_kernel(const int* __restrict__ starts, const int* __restrict__ ends,
                              const int* __restrict__ csr, const __half* __restrict__ Hh,
                              const float* __restrict__ nd, const float* __restrict__ b,
                              __half* __restrict__ Xh, const float* __restrict__ Wp,
                              const float* __restrict__ bp, float* __restrict__ out,
                              int Nn) {
    __shared__ float sW[NLAB * 65];     // [label][feat], pad 65 (PROJ only)
    __shared__ float sb_[NLAB];
    const int tid = threadIdx.x;

    if constexpr (PROJ) {
        for (int i = tid; i < 64 * NLAB; i += 256) {
            int k = i >> 3, l = i & 7;
            sW[l * 65 + k] = Wp[i];     // transpose: Wp is [feat][label]
        }
        if (tid < NLAB) sb_[tid] = bp[tid];
        __syncthreads();
    }

    const int lane = tid & 63;
    const int half32 = (lane >> 5) & 1;         // node slot within wave
    const int l32 = lane & 31;                  // lane within half
    const int g = l32 >> 3;                     // edge slot group 0..3
    const int c = lane & 7;                     // 16B col chunk

    int node = blockIdx.x * 8 + ((tid >> 6) << 1) + half32;
    const bool valid = node < Nn;
    const int nodeC = valid ? node : (Nn - 1);

    const int start = starts[nodeC];
    const int deg   = ends[nodeC] - start;      // uniform within half
    const int dmax  = max(deg, __shfl_xor(deg, 32, 64));  // wave-uniform

    float acc[8] = {0.f, 0.f, 0.f, 0.f, 0.f, 0.f, 0.f, 0.f};

    for (int base = 0; base < dmax; base += 32) {
        int off = base + l32;
        int pe = (off < deg) ? csr[start + off] : Nn;  // sentinel: zero row
        int ecm = min(dmax - base, 32);                // wave-uniform
        int nkp = (ecm + 7) >> 3;                      // uniform trip count

        for (int k = 0; k < nkp; ++k) {
            int j0 = g + 8 * k;                        // slots [8k, 8k+4)
            int j1 = j0 + 4;                           // slots [8k+4, 8k+8)
            int s0 = __shfl(pe, (lane & 32) + j0, 64); // full-wave exec
            int s1 = __shfl(pe, (lane & 32) + j1, 64);
            H8 v0, v1;
            v0.i4 = ((const int4*)(Hh + (size_t)s0 * 64))[c];  // unconditional
            v1.i4 = ((const int4*)(Hh + (size_t)s1 * 64))[c];
#pragma unroll
            for (int t = 0; t < 4; ++t) {
                H2U su;
                su.h = __hadd2(v0.h2[t], v1.h2[t]);    // v_pk_add_f16
                fma_mix2(acc[2 * t], acc[2 * t + 1], su.u);
            }
        }
    }

    // butterfly over g (lane bits 3,4) — ALL lanes end with full sums
#pragma unroll
    for (int m = 8; m <= 16; m <<= 1) {
#pragma unroll
        for (int k = 0; k < 8; ++k)
            acc[k] += __shfl_xor(acc[k], m, 64);
    }

    if constexpr (!PROJ) {
        if (g == 0 && valid) {                  // 8 lanes per half write 8 cols each
            float nm = nd[node];
            float4 b0 = ((const float4*)b)[2 * c];
            float4 b1 = ((const float4*)b)[2 * c + 1];
            H8 o;
            o.h2[0] = __floats2half2_rn(fmaxf(fmaf(acc[0], nm, b0.x), 0.f),
                                        fmaxf(fmaf(acc[1], nm, b0.y), 0.f));
            o.h2[1] = __floats2half2_rn(fmaxf(fmaf(acc[2], nm, b0.z), 0.f),
                                        fmaxf(fmaf(acc[3], nm, b0.w), 0.f));
            o.h2[2] = __floats2half2_rn(fmaxf(fmaf(acc[4], nm, b1.x), 0.f),
                                        fmaxf(fmaf(acc[5], nm, b1.y), 0.f));
            o.h2[3] = __floats2half2_rn(fmaxf(fmaf(acc[6], nm, b1.z), 0.f),
                                        fmaxf(fmaf(acc[7], nm, b1.w), 0.f));
            ((int4*)(Xh + (size_t)node * 64))[c] = o.i4;
        }
    } else {
        // x row (fp32, un-rounded): feats 8c..8c+7, replicated across g
        float nm = nd[nodeC];
        float4 b0 = ((const float4*)b)[2 * c];
        float4 b1 = ((const float4*)b)[2 * c + 1];
        float xv[8];
        xv[0] = fmaxf(fmaf(acc[0], nm, b0.x), 0.f);
        xv[1] = fmaxf(fmaf(acc[1], nm, b0.y), 0.f);
        xv[2] = fmaxf(fmaf(acc[2], nm, b0.z), 0.f);
        xv[3] = fmaxf(fmaf(acc[3], nm, b0.w), 0.f);
        xv[4] = fmaxf(fmaf(acc[4], nm, b1.x), 0.f);
        xv[5] = fmaxf(fmaf(acc[5], nm, b1.y), 0.f);
        xv[6] = fmaxf(fmaf(acc[6], nm, b1.z), 0.f);
        xv[7] = fmaxf(fmaf(acc[7], nm, b1.w), 0.f);

        // labels 2g, 2g+1 partials over feats 8c..8c+7
        const int l0 = 2 * g, l1 = l0 + 1;
        float p0 = 0.f, p1 = 0.f;
#pragma unroll
        for (int j = 0; j < 8; ++j) {
            p0 = fmaf(xv[j], sW[l0 * 65 + 8 * c + j], p0);
            p1 = fmaf(xv[j], sW[l1 * 65 + 8 * c + j], p1);
        }
        // reduce over c (bits 0..2) — all lanes get label totals for their g
        p0 += __shfl_xor(p0, 1, 64); p1 += __shfl_xor(p1, 1, 64);
        p0 += __shfl_xor(p0, 2, 64); p1 += __shfl_xor(p1, 2, 64);
        p0 += __shfl_xor(p0, 4, 64); p1 += __shfl_xor(p1, 4, 64);
        p0 += sb_[l0];
        p1 += sb_[l1];
        // softmax across the 8 labels (2 per g-group)
        float mx = fmaxf(p0, p1);
        mx = fmaxf(mx, __shfl_xor(mx, 8, 64));
        mx = fmaxf(mx, __shfl_xor(mx, 16, 64));
        float e0 = __expf(p0 - mx), e1 = __expf(p1 - mx);
        float s2 = e0 + e1;
        s2 += __shfl_xor(s2, 8, 64);
        s2 += __shfl_xor(s2, 16, 64);
        float inv = 1.0f / s2;
        if (c == 0 && valid) {                  // 4 lanes per half, 2 labels each
            float2 o = {e0 * inv, e1 * inv};
            *(float2*)(out + (size_t)node * NLAB + l0) = o;
        }
    }
}

// ---------------- launch ----------------

extern "C" void kernel_launch(void* const* d_in, const int* in_sizes, int n_in,
                              void* d_out, int out_size, void* d_ws, size_t ws_size,
                              hipStream_t stream) {
    const float* features = (const float*)d_in[0];
    const int*   edge_src = (const int*)d_in[1];
    const int*   edge_dst = (const int*)d_in[2];
    const float* W1 = (const float*)d_in[4];
    const float* b1 = (const float*)d_in[5];
    const float* W2 = (const float*)d_in[6];
    const float* b2 = (const float*)d_in[7];
    const float* Wp = (const float*)d_in[8];
    const float* bp = (const float*)d_in[9];
    float* out = (float*)d_out;

    const int N = NODES;
    const int E = in_sizes[1];

    // ---- workspace layout (~35 MB) ----
    // h has N+64 rows: row N is the sentinel zero row (written by the GEMM
    // epilogues' out-of-range lanes). dreg/sreg alias x (dead until
    // gather-L1 writes x): csr2/shist consume them strictly before
    // gather-L1, so build2's csr2 and gemm1 (writes h) are race-free.
    char* p = (char*)d_ws;
    int*   csr    = (int*)p;            p += sizeof(int) * (size_t)NHALF * CAPH;  // 7.2 MB
    int*   starts = (int*)p;            p += sizeof(int) * N;
    int*   ends   = (int*)p;            p += sizeof(int) * N;
    float* norm_s = (float*)p;          p += sizeof(float) * N;
    float* norm_d = (float*)p;          p += sizeof(float) * N;
    int*   gcur_d = (int*)p;            p += sizeof(int) * NHALF * GSTRIDE;  // zeroed
    int*   gcur_s = (int*)p;            p += sizeof(int) * NSB * GSTRIDE;    // zeroed
    p = (char*)(((size_t)p + 255) & ~(size_t)255);
    _Float16* wt1 = (_Float16*)p;       p += sizeof(_Float16) * 64 * (INF + 8);
    _Float16* wt2 = (_Float16*)p;       p += sizeof(_Float16) * 64 * (HID + 8);
    p = (char*)(((size_t)p + 255) & ~(size_t)255);
    __half* h     = (__half*)p;         p += sizeof(__half) * ((size_t)N + 64) * 64; // 12.8 MB + sentinel
    p = (char*)(((size_t)p + 255) & ~(size_t)255);
    __half* x     = (__half*)p;         p += sizeof(__half) * (size_t)N * 64; // 12.8 MB
    // aliases inside x (dead before gather-L1 writes x):
    int*            dreg = (int*)x;                                              // 7.19 MB
    unsigned short* sreg = (unsigned short*)((char*)x + sizeof(int) * (size_t)NHALF * CAPH); // 3.5 MB

    hipMemsetAsync(gcur_d, 0, sizeof(int) * (NHALF + NSB) * GSTRIDE, stream);

    // ---- build: [partition || wcvt] -> shist -> [CSR || gemm1] ----
    const int partWGs = (E + PCHUNK - 1) / PCHUNK;
    build1_kernel<<<partWGs + WCVT_WGS, 256, 0, stream>>>(edge_src, edge_dst,
                                                          gcur_d, gcur_s, dreg, sreg,
                                                          E, partWGs, W1, W2, wt1, wt2);
    shist_kernel<<<NSB, 256, 0, stream>>>(sreg, gcur_s, norm_s, N);
    build2_kernel<<<NHALF + (N + 63) / 64, 256, 0, stream>>>(dreg, gcur_d, csr, starts,
                                                             ends, norm_d,
                                                             features, norm_s, wt1, h, N);

    // ---- layer 1 gather ----
    gather_kernel<false><<<(N + 7) / 8, 256, 0, stream>>>(starts, ends, csr, h, norm_d,
                                                          b1, x, nullptr, nullptr,
                                                          nullptr, N);

    // ---- layer 2: GEMM then gather fused with projection + softmax ----
    gemm_mfma_kernel<HID, true><<<(N + 63) / 64, 256, 0, stream>>>(x, norm_s, wt2, h, N);
    gather_kernel<true><<<(N + 7) / 8, 256, 0, stream>>>(starts, ends, csr, h, norm_d,
                                                         b2, nullptr, Wp, bp, out, N);
}

// Round 9
// 232.895 us; speedup vs baseline: 1.0411x; 1.0411x over previous
//
#include <hip/hip_runtime.h>
#include <hip/hip_fp16.h>
#include <math.h>

// GCN: 2x GraphConv(norm='both') + projection + softmax.
// N=100000 nodes, E=1600000 edges, feats 128 -> 64 -> 64 -> 8. All fp32 I/O.
//
// R21 (on R20 = 242.5us): R19/R20's sentinel was NEUTRAL -> gather is
// memory-system bound (random 128B h-row reads), not VALU-bound; stop
// shaving instructions. Structural fusion instead: gatherL1 + gemm2 in one
// kernel (block = 64 nodes; gather epilogue writes fp16 rows to LDS tile
// xt[64][72], barrier, K=64 MFMA reads A-frags from LDS, writes layer-2 h
// into the old x buffer). Kills one dispatch + drain and the 25.6MB x
// round-trip. Same rounding points -> bit-identical. Everything else R20.

#define NODES   100000
#define INF     128
#define HID     64
#define NLAB    8

#define SB      512                         // nodes per src super-bucket
#define NSB     ((NODES + SB - 1) / SB)     // 196 (src side)
#define NHALF   ((NODES + 255) / 256)       // 391 dst half-buckets (256 nodes)
#define SCAP    9000                        // per-sb src cap
#define CAPH    4600                        // per-half edge cap (mean 4096, sigma~64)
#define PCHUNK  8192                        // edges per part WG (196 blocks)
#define PEPT    (PCHUNK / 256)              // 32
#define SRCMASK 0x1FFFF                     // 17 bits
#define GSTRIDE 16                          // ints; one gcur counter per 64B line

#define WCVT_ELEMS (64 * (INF + 8) + 64 * (HID + 8))
#define WCVT_WGS   ((WCVT_ELEMS + 255) / 256)

union H8 { int4 i4; __half2 h2[4]; unsigned int u[4]; };
union H2U { __half2 h; unsigned int u; };

typedef _Float16 half8 __attribute__((ext_vector_type(8)));
typedef float floatx4 __attribute__((ext_vector_type(4)));

// acc0 += (float)lo16(h2); acc1 += (float)hi16(h2) — one VOP3P mix-FMA each.
// Exact f16->f32 convert inside the FMA: bit-identical to cvt+add.
__device__ __forceinline__ void fma_mix2(float& a0, float& a1, unsigned int h2) {
    asm("v_fma_mix_f32 %0, %2, 1.0, %0 op_sel_hi:[1,0,0]\n\t"
        "v_fma_mix_f32 %1, %2, 1.0, %1 op_sel:[1,0,0] op_sel_hi:[1,0,0]"
        : "+v"(a0), "+v"(a1) : "v"(h2));
}

// ---------------- build1: partition edges by dst>>8; src vals by src>>9 ----------------
// (+ W convert in trailing blocks)

__global__ void build1_kernel(const int* __restrict__ src, const int* __restrict__ dst,
                              int* __restrict__ gcur_d, int* __restrict__ gcur_s,
                              int* __restrict__ dreg, unsigned short* __restrict__ sreg,
                              int E, int partWGs,
                              const float* __restrict__ W1, const float* __restrict__ W2,
                              _Float16* __restrict__ wt1, _Float16* __restrict__ wt2) {
    __shared__ int hd[NHALF], bd[NHALF], hs[NSB], bs[NSB];
    const int tid = threadIdx.x;

    if (blockIdx.x >= partWGs) {
        // ---- W convert: fp32 [K][64] -> fp16 transposed [64][K+8] ----
        const int N1 = 64 * (INF + 8);
        const int N2 = 64 * (HID + 8);
        int i = (blockIdx.x - partWGs) * 256 + tid;
        if (i < N1) {
            int n = i / (INF + 8), k = i % (INF + 8);
            wt1[i] = (k < INF) ? (_Float16)W1[k * 64 + n] : (_Float16)0.f;
        } else if (i < N1 + N2) {
            int j = i - N1;
            int n = j / (HID + 8), k = j % (HID + 8);
            wt2[j] = (k < HID) ? (_Float16)W2[k * 64 + n] : (_Float16)0.f;
        }
        return;
    }

    const int e0 = blockIdx.x * PCHUNK;

    for (int i = tid; i < NHALF; i += 256) { hd[i] = 0; }
    for (int i = tid; i < NSB; i += 256) { hs[i] = 0; }
    __syncthreads();

    // phase A: LDS histograms (edges re-read from L2 in phase C)
    int es[PEPT], ed[PEPT];
#pragma unroll
    for (int i = 0; i < PEPT; ++i) {
        int e = e0 + tid + i * 256;
        if (e < E) {
            es[i] = src[e]; ed[i] = dst[e];
            atomicAdd(&hd[ed[i] >> 8], 1);
            atomicAdd(&hs[es[i] >> 9], 1);
        } else es[i] = -1;
    }
    __syncthreads();

    // phase B: reserve contiguous runs (chain depth = 196 blocks;
    // line-spread counters -> 587 chains drain in parallel)
    for (int b = tid; b < NHALF; b += 256) {
        int c = hd[b]; bd[b] = c ? atomicAdd(&gcur_d[b * GSTRIDE], c) : 0;
    }
    for (int b = tid; b < NSB; b += 256) {
        int c = hs[b]; bs[b] = c ? atomicAdd(&gcur_s[b * GSTRIDE], c) : 0;
    }
    __syncthreads();
    for (int b = tid; b < NHALF; b += 256) hd[b] = 0;
    for (int b = tid; b < NSB; b += 256) hs[b] = 0;
    __syncthreads();

    // phase C: scatter into runs (dst_local(8b)<<17 | src; src_local as ushort)
#pragma unroll
    for (int i = 0; i < PEPT; ++i) {
        if (es[i] >= 0) {
            int s = es[i], d = ed[i];
            int kb = d >> 8;
            int pos = bd[kb] + atomicAdd(&hd[kb], 1);
            if (pos < CAPH) dreg[(size_t)kb * CAPH + pos] = ((d & 255) << 17) | s;
            int ks = s >> 9;
            int ps = bs[ks] + atomicAdd(&hs[ks], 1);
            if (ps < SCAP) sreg[(size_t)ks * SCAP + ps] = (unsigned short)(s & (SB - 1));
        }
    }
}

// ---------------- src-degree histogram per super-bucket -> norm_s ----------------

__global__ void shist_kernel(const unsigned short* __restrict__ sreg,
                             const int* __restrict__ gcur_s,
                             float* __restrict__ norm_s, int Nn) {
    __shared__ int hist[SB];
    const int tid = threadIdx.x;
    const int sb = blockIdx.x;
    for (int i = tid; i < SB; i += 256) hist[i] = 0;
    __syncthreads();
    const int cnt = min(gcur_s[sb * GSTRIDE], SCAP);
    const unsigned short* base = sreg + (size_t)sb * SCAP;
    for (int i = tid; i < cnt; i += 256) atomicAdd(&hist[base[i]], 1);
    __syncthreads();
    for (int t = tid; t < SB; t += 256) {
        int node = sb * SB + t;
        if (node < Nn) norm_s[node] = rsqrtf(fmaxf((float)hist[t], 1.0f));
    }
}

// ---------------- build2: csr2 (first NHALF blocks) || gemm1 MFMA (rest) ----------------
// csr2: per-half-bucket counting sort (own edges only, wave-scan) -> exact
// CSR + norm_d. gemm1: Hh = fp16( norm_s * (X@W1) ); row Nn (sentinel) = 0.
// Independent (dreg aliases x, not h).

__global__ void build2_kernel(const int* __restrict__ dreg, const int* __restrict__ gcur_d,
                              int* __restrict__ csr, int* __restrict__ starts,
                              int* __restrict__ ends, float* __restrict__ norm_d,
                              const float* __restrict__ Xv, const float* __restrict__ norm,
                              const _Float16* __restrict__ Wt, __half* __restrict__ Hh,
                              int Nn) {
    __shared__ union SMem {
        struct CS { int hist[256]; int cur[256]; int wsum[4]; int sorted[CAPH]; } c;
        _Float16 w[64 * (INF + 8)];
    } sm;
    const int tid = threadIdx.x;

    if (blockIdx.x < NHALF) {
        // ---- csr2: WG j owns nodes [j*256, j*256+256) = dst bucket j ----
        const int j = blockIdx.x;
        const int cnt = min(gcur_d[j * GSTRIDE], CAPH);
        const int* reg = dreg + (size_t)j * CAPH;

        sm.c.hist[tid] = 0;
        __syncthreads();

        for (int i = tid; i < cnt; i += 256)
            atomicAdd(&sm.c.hist[(reg[i] >> 17) & 255], 1);
        __syncthreads();

        // exclusive scan over 256: wave shfl_up scan + 4-word combine
        const int lane = tid & 63, wid = tid >> 6;
        int deg_n = sm.c.hist[tid];
        int v = deg_n;
#pragma unroll
        for (int off = 1; off < 64; off <<= 1) {
            int u = __shfl_up(v, off, 64);
            if (lane >= off) v += u;
        }
        if (lane == 63) sm.c.wsum[wid] = v;
        __syncthreads();
        int wadd = 0;
#pragma unroll
        for (int q = 0; q < 3; ++q) wadd += (q < wid) ? sm.c.wsum[q] : 0;
        int st = v + wadd - deg_n;

        int node = j * 256 + tid;
        if (node < Nn) {
            int gs = j * CAPH + st;
            int dcl = min(deg_n, max(CAPH - st, 0));
            starts[node] = gs;
            ends[node]   = gs + dcl;
            norm_d[node] = rsqrtf(fmaxf((float)deg_n, 1.0f));
        }
        sm.c.cur[tid] = st;
        __syncthreads();

        for (int i = tid; i < cnt; i += 256) {
            int pe = reg[i];
            int pos = atomicAdd(&sm.c.cur[(pe >> 17) & 255], 1);
            if (pos < CAPH) sm.c.sorted[pos] = pe & SRCMASK;
        }
        __syncthreads();

        for (int i = tid; i < cnt; i += 256) csr[(size_t)j * CAPH + i] = sm.c.sorted[i];
        return;
    }

    // ---- gemm1: block = 64 rows, 4 waves x 16; K=128 fp32 input ----
    constexpr int K = INF;
    constexpr int KP = K + 8;
    const int bid = blockIdx.x - NHALF;

    constexpr int NI4 = 64 * KP * 2 / 16;
    for (int i = tid; i < NI4; i += 256)
        ((int4*)sm.w)[i] = ((const int4*)Wt)[i];
    __syncthreads();

    const int w = tid >> 6, lane = tid & 63;
    const int m16 = lane & 15, quad = lane >> 4;
    const int rowA = bid * 64 + w * 16 + m16;
    const int rowC = (rowA < Nn) ? rowA : (Nn - 1);

    floatx4 acc0 = {0.f, 0.f, 0.f, 0.f};
    floatx4 acc1 = acc0, acc2 = acc0, acc3 = acc0;

#pragma unroll
    for (int c = 0; c < K / 32; ++c) {
        const int k0 = c * 32 + quad * 8;
        const float* xrow = Xv + (size_t)rowC * K;
        float4 xa = *(const float4*)(xrow + k0);
        float4 xb = *(const float4*)(xrow + k0 + 4);
        half8 a;
        a[0] = (_Float16)xa.x; a[1] = (_Float16)xa.y;
        a[2] = (_Float16)xa.z; a[3] = (_Float16)xa.w;
        a[4] = (_Float16)xb.x; a[5] = (_Float16)xb.y;
        a[6] = (_Float16)xb.z; a[7] = (_Float16)xb.w;
        half8 b0 = *(const half8*)&sm.w[(0 * 16 + m16) * KP + k0];
        half8 b1 = *(const half8*)&sm.w[(1 * 16 + m16) * KP + k0];
        half8 b2 = *(const half8*)&sm.w[(2 * 16 + m16) * KP + k0];
        half8 b3 = *(const half8*)&sm.w[(3 * 16 + m16) * KP + k0];
        acc0 = __builtin_amdgcn_mfma_f32_16x16x32_f16(a, b0, acc0, 0, 0, 0);
        acc1 = __builtin_amdgcn_mfma_f32_16x16x32_f16(a, b1, acc1, 0, 0, 0);
        acc2 = __builtin_amdgcn_mfma_f32_16x16x32_f16(a, b2, acc2, 0, 0, 0);
        acc3 = __builtin_amdgcn_mfma_f32_16x16x32_f16(a, b3, acc3, 0, 0, 0);
    }

    const int rbase = bid * 64 + w * 16 + quad * 4;
    floatx4 accs[4] = {acc0, acc1, acc2, acc3};
#pragma unroll
    for (int i = 0; i < 4; ++i) {
        int grow = rbase + i;
        if (grow < Nn) {
            float nm = norm[grow];
            __half* o = Hh + (size_t)grow * 64 + m16;
#pragma unroll
            for (int t = 0; t < 4; ++t)
                o[16 * t] = (__half)(accs[t][i] * nm);
        } else if (grow == Nn) {               // sentinel zero row for gather
            __half* o = Hh + (size_t)grow * 64 + m16;
#pragma unroll
            for (int t = 0; t < 4; ++t)
                o[16 * t] = (__half)0.f;
        }
    }
}

// ---------------- fused gatherL1 + gemm2: block = 64 nodes ----------------
// Phase 1: 2-node-per-wave pull gather (8 iterations/wave), epilogue writes
// relu(norm_d*agg + b1) as fp16 into LDS tile xt[64][72] (pad-72: 2-way
// banks on ds_read_b128). Phase 2: K=64 MFMA GEMM, A-frags from xt, output
// fp16( norm_s * (xt@W2) ) -> Xout rows (sentinel row Nn = 0). Removes the
// 25.6MB x round-trip and one dispatch drain. Same rounding points as the
// split kernels -> bit-identical.

__global__ void gather_gemm_kernel(const int* __restrict__ starts, const int* __restrict__ ends,
                                   const int* __restrict__ csr, const __half* __restrict__ Hh,
                                   const float* __restrict__ nd, const float* __restrict__ b,
                                   const float* __restrict__ norm, const _Float16* __restrict__ Wt,
                                   __half* __restrict__ Xout, int Nn) {
    constexpr int K = HID;
    constexpr int KP = K + 8;
    __shared__ _Float16 sWt[64 * KP];   // 9.2 KB
    __shared__ _Float16 xt[64 * KP];    // 9.2 KB x-tile

    const int tid = threadIdx.x;
    constexpr int NI4 = 64 * KP * 2 / 16;
    for (int i = tid; i < NI4; i += 256)
        ((int4*)sWt)[i] = ((const int4*)Wt)[i];
    // (barrier below covers sWt before phase 2 use)

    const int lane = tid & 63;
    const int half32 = (lane >> 5) & 1;         // node slot within wave
    const int l32 = lane & 31;                  // lane within half
    const int g = l32 >> 3;                     // edge slot group 0..3
    const int c = lane & 7;                     // 16B col chunk
    const int w = tid >> 6;
    const int m16 = lane & 15, quad = lane >> 4;

    // ---- phase 1: gather 16 nodes per wave (2 per iteration) ----
#pragma unroll 1
    for (int it = 0; it < 8; ++it) {
        const int nloc = w * 16 + it * 2 + half32;       // 0..63
        const int node = blockIdx.x * 64 + nloc;
        const int nodeC = (node < Nn) ? node : (Nn - 1);

        const int start = starts[nodeC];
        const int deg   = ends[nodeC] - start;
        const int dmax  = max(deg, __shfl_xor(deg, 32, 64));

        float acc[8] = {0.f, 0.f, 0.f, 0.f, 0.f, 0.f, 0.f, 0.f};

        for (int base = 0; base < dmax; base += 32) {
            int off = base + l32;
            int pe = (off < deg) ? csr[start + off] : Nn;  // sentinel: zero row
            int ecm = min(dmax - base, 32);
            int nkp = (ecm + 7) >> 3;

            for (int k = 0; k < nkp; ++k) {
                int j0 = g + 8 * k;
                int j1 = j0 + 4;
                int s0 = __shfl(pe, (lane & 32) + j0, 64);
                int s1 = __shfl(pe, (lane & 32) + j1, 64);
                H8 v0, v1;
                v0.i4 = ((const int4*)(Hh + (size_t)s0 * 64))[c];
                v1.i4 = ((const int4*)(Hh + (size_t)s1 * 64))[c];
#pragma unroll
                for (int t = 0; t < 4; ++t) {
                    H2U su;
                    su.h = __hadd2(v0.h2[t], v1.h2[t]);
                    fma_mix2(acc[2 * t], acc[2 * t + 1], su.u);
                }
            }
        }

#pragma unroll
        for (int m = 8; m <= 16; m <<= 1) {
#pragma unroll
            for (int k = 0; k < 8; ++k)
                acc[k] += __shfl_xor(acc[k], m, 64);
        }

        if (g == 0) {                           // 8 lanes per half -> LDS row
            float nm = nd[nodeC];
            float4 bb0 = ((const float4*)b)[2 * c];
            float4 bb1 = ((const float4*)b)[2 * c + 1];
            H8 o;
            o.h2[0] = __floats2half2_rn(fmaxf(fmaf(acc[0], nm, bb0.x), 0.f),
                                        fmaxf(fmaf(acc[1], nm, bb0.y), 0.f));
            o.h2[1] = __floats2half2_rn(fmaxf(fmaf(acc[2], nm, bb0.z), 0.f),
                                        fmaxf(fmaf(acc[3], nm, bb0.w), 0.f));
            o.h2[2] = __floats2half2_rn(fmaxf(fmaf(acc[4], nm, bb1.x), 0.f),
                                        fmaxf(fmaf(acc[5], nm, bb1.y), 0.f));
            o.h2[3] = __floats2half2_rn(fmaxf(fmaf(acc[6], nm, bb1.z), 0.f),
                                        fmaxf(fmaf(acc[7], nm, bb1.w), 0.f));
            *(int4*)(xt + nloc * KP + c * 8) = o.i4;
        }
    }
    __syncthreads();

    // ---- phase 2: gemm2, A from xt ----
    const int rowL = w * 16 + m16;

    floatx4 acc0 = {0.f, 0.f, 0.f, 0.f};
    floatx4 acc1 = acc0, acc2 = acc0, acc3 = acc0;

#pragma unroll
    for (int cc = 0; cc < K / 32; ++cc) {
        const int k0 = cc * 32 + quad * 8;
        half8 a = *(const half8*)&xt[rowL * KP + k0];
        half8 b0 = *(const half8*)&sWt[(0 * 16 + m16) * KP + k0];
        half8 b1 = *(const half8*)&sWt[(1 * 16 + m16) * KP + k0];
        half8 b2 = *(const half8*)&sWt[(2 * 16 + m16) * KP + k0];
        half8 b3 = *(const half8*)&sWt[(3 * 16 + m16) * KP + k0];
        acc0 = __builtin_amdgcn_mfma_f32_16x16x32_f16(a, b0, acc0, 0, 0, 0);
        acc1 = __builtin_amdgcn_mfma_f32_16x16x32_f16(a, b1, acc1, 0, 0, 0);
        acc2 = __builtin_amdgcn_mfma_f32_16x16x32_f16(a, b2, acc2, 0, 0, 0);
        acc3 = __builtin_amdgcn_mfma_f32_16x16x32_f16(a, b3, acc3, 0, 0, 0);
    }

    const int rbase = blockIdx.x * 64 + w * 16 + quad * 4;
    floatx4 accs[4] = {acc0, acc1, acc2, acc3};
#pragma unroll
    for (int i = 0; i < 4; ++i) {
        int grow = rbase + i;
        if (grow < Nn) {
            float nm = norm[grow];
            __half* o = Xout + (size_t)grow * 64 + m16;
#pragma unroll
            for (int t = 0; t < 4; ++t)
                o[16 * t] = (__half)(accs[t][i] * nm);
        } else if (grow == Nn) {               // sentinel zero row for gatherL2
            __half* o = Xout + (size_t)grow * 64 + m16;
#pragma unroll
            for (int t = 0; t < 4; ++t)
                o[16 * t] = (__half)0.f;
        }
    }
}

// ---------------- pull gather L2 + fused projection/softmax ----------------
// 2 nodes per wave; sentinel tail slots; fma_mix accumulate. Epilogue:
// x@Wp + bp + softmax in-register (labels 2/g-group, LDS Wp transposed
// pad-65, butterflies over c then g; c==0 lanes store float2).

__global__ void gather_proj_kernel(const int* __restrict__ starts, const int* __restrict__ ends,
                                   const int* __restrict__ csr, const __half* __restrict__ Hh,
                                   const float* __restrict__ nd, const float* __restrict__ b,
                                   const float* __restrict__ Wp, const float* __restrict__ bp,
                                   float* __restrict__ out, int Nn) {
    __shared__ float sW[NLAB * 65];     // [label][feat], pad 65
    __shared__ float sb_[NLAB];
    const int tid = threadIdx.x;

    for (int i = tid; i < 64 * NLAB; i += 256) {
        int k = i >> 3, l = i & 7;
        sW[l * 65 + k] = Wp[i];         // transpose: Wp is [feat][label]
    }
    if (tid < NLAB) sb_[tid] = bp[tid];
    __syncthreads();

    const int lane = tid & 63;
    const int half32 = (lane >> 5) & 1;
    const int l32 = lane & 31;
    const int g = l32 >> 3;
    const int c = lane & 7;

    int node = blockIdx.x * 8 + ((tid >> 6) << 1) + half32;
    const bool valid = node < Nn;
    const int nodeC = valid ? node : (Nn - 1);

    const int start = starts[nodeC];
    const int deg   = ends[nodeC] - start;
    const int dmax  = max(deg, __shfl_xor(deg, 32, 64));

    float acc[8] = {0.f, 0.f, 0.f, 0.f, 0.f, 0.f, 0.f, 0.f};

    for (int base = 0; base < dmax; base += 32) {
        int off = base + l32;
        int pe = (off < deg) ? csr[start + off] : Nn;  // sentinel: zero row
        int ecm = min(dmax - base, 32);
        int nkp = (ecm + 7) >> 3;

        for (int k = 0; k < nkp; ++k) {
            int j0 = g + 8 * k;
            int j1 = j0 + 4;
            int s0 = __shfl(pe, (lane & 32) + j0, 64);
            int s1 = __shfl(pe, (lane & 32) + j1, 64);
            H8 v0, v1;
            v0.i4 = ((const int4*)(Hh + (size_t)s0 * 64))[c];
            v1.i4 = ((const int4*)(Hh + (size_t)s1 * 64))[c];
#pragma unroll
            for (int t = 0; t < 4; ++t) {
                H2U su;
                su.h = __hadd2(v0.h2[t], v1.h2[t]);
                fma_mix2(acc[2 * t], acc[2 * t + 1], su.u);
            }
        }
    }

#pragma unroll
    for (int m = 8; m <= 16; m <<= 1) {
#pragma unroll
        for (int k = 0; k < 8; ++k)
            acc[k] += __shfl_xor(acc[k], m, 64);
    }

    // x row (fp32, un-rounded): feats 8c..8c+7, replicated across g
    float nm = nd[nodeC];
    float4 b0 = ((const float4*)b)[2 * c];
    float4 b1 = ((const float4*)b)[2 * c + 1];
    float xv[8];
    xv[0] = fmaxf(fmaf(acc[0], nm, b0.x), 0.f);
    xv[1] = fmaxf(fmaf(acc[1], nm, b0.y), 0.f);
    xv[2] = fmaxf(fmaf(acc[2], nm, b0.z), 0.f);
    xv[3] = fmaxf(fmaf(acc[3], nm, b0.w), 0.f);
    xv[4] = fmaxf(fmaf(acc[4], nm, b1.x), 0.f);
    xv[5] = fmaxf(fmaf(acc[5], nm, b1.y), 0.f);
    xv[6] = fmaxf(fmaf(acc[6], nm, b1.z), 0.f);
    xv[7] = fmaxf(fmaf(acc[7], nm, b1.w), 0.f);

    const int l0 = 2 * g, l1 = l0 + 1;
    float p0 = 0.f, p1 = 0.f;
#pragma unroll
    for (int j = 0; j < 8; ++j) {
        p0 = fmaf(xv[j], sW[l0 * 65 + 8 * c + j], p0);
        p1 = fmaf(xv[j], sW[l1 * 65 + 8 * c + j], p1);
    }
    p0 += __shfl_xor(p0, 1, 64); p1 += __shfl_xor(p1, 1, 64);
    p0 += __shfl_xor(p0, 2, 64); p1 += __shfl_xor(p1, 2, 64);
    p0 += __shfl_xor(p0, 4, 64); p1 += __shfl_xor(p1, 4, 64);
    p0 += sb_[l0];
    p1 += sb_[l1];
    float mx = fmaxf(p0, p1);
    mx = fmaxf(mx, __shfl_xor(mx, 8, 64));
    mx = fmaxf(mx, __shfl_xor(mx, 16, 64));
    float e0 = __expf(p0 - mx), e1 = __expf(p1 - mx);
    float s2 = e0 + e1;
    s2 += __shfl_xor(s2, 8, 64);
    s2 += __shfl_xor(s2, 16, 64);
    float inv = 1.0f / s2;
    if (c == 0 && valid) {
        float2 o = {e0 * inv, e1 * inv};
        *(float2*)(out + (size_t)node * NLAB + l0) = o;
    }
}

// ---------------- launch ----------------

extern "C" void kernel_launch(void* const* d_in, const int* in_sizes, int n_in,
                              void* d_out, int out_size, void* d_ws, size_t ws_size,
                              hipStream_t stream) {
    const float* features = (const float*)d_in[0];
    const int*   edge_src = (const int*)d_in[1];
    const int*   edge_dst = (const int*)d_in[2];
    const float* W1 = (const float*)d_in[4];
    const float* b1 = (const float*)d_in[5];
    const float* W2 = (const float*)d_in[6];
    const float* b2 = (const float*)d_in[7];
    const float* Wp = (const float*)d_in[8];
    const float* bp = (const float*)d_in[9];
    float* out = (float*)d_out;

    const int N = NODES;
    const int E = in_sizes[1];

    // ---- workspace layout (~35 MB) ----
    // h and x both have N+64 rows (row N = sentinel zero row). dreg/sreg
    // alias x (dead until gather_gemm writes x): csr2/shist consume them
    // strictly before, so build2's csr2 and gemm1 (writes h) are race-free.
    char* p = (char*)d_ws;
    int*   csr    = (int*)p;            p += sizeof(int) * (size_t)NHALF * CAPH;  // 7.2 MB
    int*   starts = (int*)p;            p += sizeof(int) * N;
    int*   ends   = (int*)p;            p += sizeof(int) * N;
    float* norm_s = (float*)p;          p += sizeof(float) * N;
    float* norm_d = (float*)p;          p += sizeof(float) * N;
    int*   gcur_d = (int*)p;            p += sizeof(int) * NHALF * GSTRIDE;  // zeroed
    int*   gcur_s = (int*)p;            p += sizeof(int) * NSB * GSTRIDE;    // zeroed
    p = (char*)(((size_t)p + 255) & ~(size_t)255);
    _Float16* wt1 = (_Float16*)p;       p += sizeof(_Float16) * 64 * (INF + 8);
    _Float16* wt2 = (_Float16*)p;       p += sizeof(_Float16) * 64 * (HID + 8);
    p = (char*)(((size_t)p + 255) & ~(size_t)255);
    __half* h     = (__half*)p;         p += sizeof(__half) * ((size_t)N + 64) * 64; // + sentinel
    p = (char*)(((size_t)p + 255) & ~(size_t)255);
    __half* x     = (__half*)p;         p += sizeof(__half) * ((size_t)N + 64) * 64; // + sentinel
    // aliases inside x (dead before gather_gemm writes x):
    int*            dreg = (int*)x;                                              // 7.19 MB
    unsigned short* sreg = (unsigned short*)((char*)x + sizeof(int) * (size_t)NHALF * CAPH); // 3.5 MB

    hipMemsetAsync(gcur_d, 0, sizeof(int) * (NHALF + NSB) * GSTRIDE, stream);

    // ---- build: [partition || wcvt] -> shist -> [CSR || gemm1] ----
    const int partWGs = (E + PCHUNK - 1) / PCHUNK;
    build1_kernel<<<partWGs + WCVT_WGS, 256, 0, stream>>>(edge_src, edge_dst,
                                                          gcur_d, gcur_s, dreg, sreg,
                                                          E, partWGs, W1, W2, wt1, wt2);
    shist_kernel<<<NSB, 256, 0, stream>>>(sreg, gcur_s, norm_s, N);
    build2_kernel<<<NHALF + (N + 63) / 64, 256, 0, stream>>>(dreg, gcur_d, csr, starts,
                                                             ends, norm_d,
                                                             features, norm_s, wt1, h, N);

    // ---- fused: gatherL1 (h -> LDS tile) + gemm2 (-> x, sentinel) ----
    gather_gemm_kernel<<<(N + 63) / 64, 256, 0, stream>>>(starts, ends, csr, h, norm_d,
                                                          b1, norm_s, wt2, x, N);

    // ---- gatherL2 + projection + softmax ----
    gather_proj_kernel<<<(N + 7) / 8, 256, 0, stream>>>(starts, ends, csr, x, norm_d,
                                                        b2, Wp, bp, out, N);
}

// Round 10
// 228.306 us; speedup vs baseline: 1.0620x; 1.0201x over previous
//
#include <hip/hip_runtime.h>
#include <hip/hip_fp16.h>
#include <math.h>

// GCN: 2x GraphConv(norm='both') + projection + softmax.
// N=100000 nodes, E=1600000 edges, feats 128 -> 64 -> 64 -> 8. All fp32 I/O.
//
// R22 (on R21 = 232.9us): build1 was latency-STARVED (occ 6.8% = 1 wave/
// SIMD; VALU 3%, HBM 10%): 196 blocks x 256 threads left phases A/C (8
// dependent load/scatter rounds) with no latency hiding. Block size ->
// 1024 threads, PCHUNK unchanged: chain depth stays 196 (R17's lever),
// intra-block waves x4 (16 waves/block = 4/SIMD). Phase-B counter loops
// collapse to one round. wcvt re-indexed for 1024. No numeric change.
// Everything else frozen at R21.

#define NODES   100000
#define INF     128
#define HID     64
#define NLAB    8

#define SB      512                         // nodes per src super-bucket
#define NSB     ((NODES + SB - 1) / SB)     // 196 (src side)
#define NHALF   ((NODES + 255) / 256)       // 391 dst half-buckets (256 nodes)
#define SCAP    9000                        // per-sb src cap
#define CAPH    4600                        // per-half edge cap (mean 4096, sigma~64)
#define PCHUNK  8192                        // edges per part WG (196 blocks)
#define B1T     1024                        // build1 threads per block
#define PEPT    (PCHUNK / B1T)              // 8
#define SRCMASK 0x1FFFF                     // 17 bits
#define GSTRIDE 16                          // ints; one gcur counter per 64B line

#define WCVT_ELEMS (64 * (INF + 8) + 64 * (HID + 8))
#define WCVT_WGS   ((WCVT_ELEMS + B1T - 1) / B1T)

union H8 { int4 i4; __half2 h2[4]; unsigned int u[4]; };
union H2U { __half2 h; unsigned int u; };

typedef _Float16 half8 __attribute__((ext_vector_type(8)));
typedef float floatx4 __attribute__((ext_vector_type(4)));

// acc0 += (float)lo16(h2); acc1 += (float)hi16(h2) — one VOP3P mix-FMA each.
// Exact f16->f32 convert inside the FMA: bit-identical to cvt+add.
__device__ __forceinline__ void fma_mix2(float& a0, float& a1, unsigned int h2) {
    asm("v_fma_mix_f32 %0, %2, 1.0, %0 op_sel_hi:[1,0,0]\n\t"
        "v_fma_mix_f32 %1, %2, 1.0, %1 op_sel:[1,0,0] op_sel_hi:[1,0,0]"
        : "+v"(a0), "+v"(a1) : "v"(h2));
}

// ---------------- build1: partition edges by dst>>8; src vals by src>>9 ----------------
// 1024 threads/block (+ W convert in trailing blocks)

__global__ __launch_bounds__(B1T)
void build1_kernel(const int* __restrict__ src, const int* __restrict__ dst,
                   int* __restrict__ gcur_d, int* __restrict__ gcur_s,
                   int* __restrict__ dreg, unsigned short* __restrict__ sreg,
                   int E, int partWGs,
                   const float* __restrict__ W1, const float* __restrict__ W2,
                   _Float16* __restrict__ wt1, _Float16* __restrict__ wt2) {
    __shared__ int hd[NHALF], bd[NHALF], hs[NSB], bs[NSB];
    const int tid = threadIdx.x;

    if (blockIdx.x >= partWGs) {
        // ---- W convert: fp32 [K][64] -> fp16 transposed [64][K+8] ----
        const int N1 = 64 * (INF + 8);
        const int N2 = 64 * (HID + 8);
        int i = (blockIdx.x - partWGs) * B1T + tid;
        if (i < N1) {
            int n = i / (INF + 8), k = i % (INF + 8);
            wt1[i] = (k < INF) ? (_Float16)W1[k * 64 + n] : (_Float16)0.f;
        } else if (i < N1 + N2) {
            int j = i - N1;
            int n = j / (HID + 8), k = j % (HID + 8);
            wt2[j] = (k < HID) ? (_Float16)W2[k * 64 + n] : (_Float16)0.f;
        }
        return;
    }

    const int e0 = blockIdx.x * PCHUNK;

    for (int i = tid; i < NHALF; i += B1T) { hd[i] = 0; }
    for (int i = tid; i < NSB; i += B1T) { hs[i] = 0; }
    __syncthreads();

    // phase A: LDS histograms (edges re-read from L2 in phase C)
    int es[PEPT], ed[PEPT];
#pragma unroll
    for (int i = 0; i < PEPT; ++i) {
        int e = e0 + tid + i * B1T;
        if (e < E) {
            es[i] = src[e]; ed[i] = dst[e];
            atomicAdd(&hd[ed[i] >> 8], 1);
            atomicAdd(&hs[es[i] >> 9], 1);
        } else es[i] = -1;
    }
    __syncthreads();

    // phase B: reserve contiguous runs (chain depth = 196 blocks;
    // line-spread counters -> 587 chains drain in parallel; one round)
    if (tid < NHALF) {
        int c = hd[tid]; bd[tid] = c ? atomicAdd(&gcur_d[tid * GSTRIDE], c) : 0;
    }
    if (tid < NSB) {
        int c = hs[tid]; bs[tid] = c ? atomicAdd(&gcur_s[tid * GSTRIDE], c) : 0;
    }
    __syncthreads();
    for (int b = tid; b < NHALF; b += B1T) hd[b] = 0;
    for (int b = tid; b < NSB; b += B1T) hs[b] = 0;
    __syncthreads();

    // phase C: scatter into runs (dst_local(8b)<<17 | src; src_local as ushort)
#pragma unroll
    for (int i = 0; i < PEPT; ++i) {
        if (es[i] >= 0) {
            int s = es[i], d = ed[i];
            int kb = d >> 8;
            int pos = bd[kb] + atomicAdd(&hd[kb], 1);
            if (pos < CAPH) dreg[(size_t)kb * CAPH + pos] = ((d & 255) << 17) | s;
            int ks = s >> 9;
            int ps = bs[ks] + atomicAdd(&hs[ks], 1);
            if (ps < SCAP) sreg[(size_t)ks * SCAP + ps] = (unsigned short)(s & (SB - 1));
        }
    }
}

// ---------------- src-degree histogram per super-bucket -> norm_s ----------------

__global__ void shist_kernel(const unsigned short* __restrict__ sreg,
                             const int* __restrict__ gcur_s,
                             float* __restrict__ norm_s, int Nn) {
    __shared__ int hist[SB];
    const int tid = threadIdx.x;
    const int sb = blockIdx.x;
    for (int i = tid; i < SB; i += 256) hist[i] = 0;
    __syncthreads();
    const int cnt = min(gcur_s[sb * GSTRIDE], SCAP);
    const unsigned short* base = sreg + (size_t)sb * SCAP;
    for (int i = tid; i < cnt; i += 256) atomicAdd(&hist[base[i]], 1);
    __syncthreads();
    for (int t = tid; t < SB; t += 256) {
        int node = sb * SB + t;
        if (node < Nn) norm_s[node] = rsqrtf(fmaxf((float)hist[t], 1.0f));
    }
}

// ---------------- build2: csr2 (first NHALF blocks) || gemm1 MFMA (rest) ----------------
// csr2: per-half-bucket counting sort (own edges only, wave-scan) -> exact
// CSR + norm_d. gemm1: Hh = fp16( norm_s * (X@W1) ); row Nn (sentinel) = 0.
// Independent (dreg aliases x, not h).

__global__ void build2_kernel(const int* __restrict__ dreg, const int* __restrict__ gcur_d,
                              int* __restrict__ csr, int* __restrict__ starts,
                              int* __restrict__ ends, float* __restrict__ norm_d,
                              const float* __restrict__ Xv, const float* __restrict__ norm,
                              const _Float16* __restrict__ Wt, __half* __restrict__ Hh,
                              int Nn) {
    __shared__ union SMem {
        struct CS { int hist[256]; int cur[256]; int wsum[4]; int sorted[CAPH]; } c;
        _Float16 w[64 * (INF + 8)];
    } sm;
    const int tid = threadIdx.x;

    if (blockIdx.x < NHALF) {
        // ---- csr2: WG j owns nodes [j*256, j*256+256) = dst bucket j ----
        const int j = blockIdx.x;
        const int cnt = min(gcur_d[j * GSTRIDE], CAPH);
        const int* reg = dreg + (size_t)j * CAPH;

        sm.c.hist[tid] = 0;
        __syncthreads();

        for (int i = tid; i < cnt; i += 256)
            atomicAdd(&sm.c.hist[(reg[i] >> 17) & 255], 1);
        __syncthreads();

        // exclusive scan over 256: wave shfl_up scan + 4-word combine
        const int lane = tid & 63, wid = tid >> 6;
        int deg_n = sm.c.hist[tid];
        int v = deg_n;
#pragma unroll
        for (int off = 1; off < 64; off <<= 1) {
            int u = __shfl_up(v, off, 64);
            if (lane >= off) v += u;
        }
        if (lane == 63) sm.c.wsum[wid] = v;
        __syncthreads();
        int wadd = 0;
#pragma unroll
        for (int q = 0; q < 3; ++q) wadd += (q < wid) ? sm.c.wsum[q] : 0;
        int st = v + wadd - deg_n;

        int node = j * 256 + tid;
        if (node < Nn) {
            int gs = j * CAPH + st;
            int dcl = min(deg_n, max(CAPH - st, 0));
            starts[node] = gs;
            ends[node]   = gs + dcl;
            norm_d[node] = rsqrtf(fmaxf((float)deg_n, 1.0f));
        }
        sm.c.cur[tid] = st;
        __syncthreads();

        for (int i = tid; i < cnt; i += 256) {
            int pe = reg[i];
            int pos = atomicAdd(&sm.c.cur[(pe >> 17) & 255], 1);
            if (pos < CAPH) sm.c.sorted[pos] = pe & SRCMASK;
        }
        __syncthreads();

        for (int i = tid; i < cnt; i += 256) csr[(size_t)j * CAPH + i] = sm.c.sorted[i];
        return;
    }

    // ---- gemm1: block = 64 rows, 4 waves x 16; K=128 fp32 input ----
    constexpr int K = INF;
    constexpr int KP = K + 8;
    const int bid = blockIdx.x - NHALF;

    constexpr int NI4 = 64 * KP * 2 / 16;
    for (int i = tid; i < NI4; i += 256)
        ((int4*)sm.w)[i] = ((const int4*)Wt)[i];
    __syncthreads();

    const int w = tid >> 6, lane = tid & 63;
    const int m16 = lane & 15, quad = lane >> 4;
    const int rowA = bid * 64 + w * 16 + m16;
    const int rowC = (rowA < Nn) ? rowA : (Nn - 1);

    floatx4 acc0 = {0.f, 0.f, 0.f, 0.f};
    floatx4 acc1 = acc0, acc2 = acc0, acc3 = acc0;

#pragma unroll
    for (int c = 0; c < K / 32; ++c) {
        const int k0 = c * 32 + quad * 8;
        const float* xrow = Xv + (size_t)rowC * K;
        float4 xa = *(const float4*)(xrow + k0);
        float4 xb = *(const float4*)(xrow + k0 + 4);
        half8 a;
        a[0] = (_Float16)xa.x; a[1] = (_Float16)xa.y;
        a[2] = (_Float16)xa.z; a[3] = (_Float16)xa.w;
        a[4] = (_Float16)xb.x; a[5] = (_Float16)xb.y;
        a[6] = (_Float16)xb.z; a[7] = (_Float16)xb.w;
        half8 b0 = *(const half8*)&sm.w[(0 * 16 + m16) * KP + k0];
        half8 b1 = *(const half8*)&sm.w[(1 * 16 + m16) * KP + k0];
        half8 b2 = *(const half8*)&sm.w[(2 * 16 + m16) * KP + k0];
        half8 b3 = *(const half8*)&sm.w[(3 * 16 + m16) * KP + k0];
        acc0 = __builtin_amdgcn_mfma_f32_16x16x32_f16(a, b0, acc0, 0, 0, 0);
        acc1 = __builtin_amdgcn_mfma_f32_16x16x32_f16(a, b1, acc1, 0, 0, 0);
        acc2 = __builtin_amdgcn_mfma_f32_16x16x32_f16(a, b2, acc2, 0, 0, 0);
        acc3 = __builtin_amdgcn_mfma_f32_16x16x32_f16(a, b3, acc3, 0, 0, 0);
    }

    const int rbase = bid * 64 + w * 16 + quad * 4;
    floatx4 accs[4] = {acc0, acc1, acc2, acc3};
#pragma unroll
    for (int i = 0; i < 4; ++i) {
        int grow = rbase + i;
        if (grow < Nn) {
            float nm = norm[grow];
            __half* o = Hh + (size_t)grow * 64 + m16;
#pragma unroll
            for (int t = 0; t < 4; ++t)
                o[16 * t] = (__half)(accs[t][i] * nm);
        } else if (grow == Nn) {               // sentinel zero row for gather
            __half* o = Hh + (size_t)grow * 64 + m16;
#pragma unroll
            for (int t = 0; t < 4; ++t)
                o[16 * t] = (__half)0.f;
        }
    }
}

// ---------------- fused gatherL1 + gemm2: block = 64 nodes ----------------
// Phase 1: 2-node-per-wave pull gather (8 iterations/wave), epilogue writes
// relu(norm_d*agg + b1) as fp16 into LDS tile xt[64][72] (pad-72: 2-way
// banks on ds_read_b128). Phase 2: K=64 MFMA GEMM, A-frags from xt, output
// fp16( norm_s * (xt@W2) ) -> Xout rows (sentinel row Nn = 0).

__global__ void gather_gemm_kernel(const int* __restrict__ starts, const int* __restrict__ ends,
                                   const int* __restrict__ csr, const __half* __restrict__ Hh,
                                   const float* __restrict__ nd, const float* __restrict__ b,
                                   const float* __restrict__ norm, const _Float16* __restrict__ Wt,
                                   __half* __restrict__ Xout, int Nn) {
    constexpr int K = HID;
    constexpr int KP = K + 8;
    __shared__ _Float16 sWt[64 * KP];   // 9.2 KB
    __shared__ _Float16 xt[64 * KP];    // 9.2 KB x-tile

    const int tid = threadIdx.x;
    constexpr int NI4 = 64 * KP * 2 / 16;
    for (int i = tid; i < NI4; i += 256)
        ((int4*)sWt)[i] = ((const int4*)Wt)[i];
    // (barrier below covers sWt before phase 2 use)

    const int lane = tid & 63;
    const int half32 = (lane >> 5) & 1;         // node slot within wave
    const int l32 = lane & 31;                  // lane within half
    const int g = l32 >> 3;                     // edge slot group 0..3
    const int c = lane & 7;                     // 16B col chunk
    const int w = tid >> 6;
    const int m16 = lane & 15, quad = lane >> 4;

    // ---- phase 1: gather 16 nodes per wave (2 per iteration) ----
#pragma unroll 1
    for (int it = 0; it < 8; ++it) {
        const int nloc = w * 16 + it * 2 + half32;       // 0..63
        const int node = blockIdx.x * 64 + nloc;
        const int nodeC = (node < Nn) ? node : (Nn - 1);

        const int start = starts[nodeC];
        const int deg   = ends[nodeC] - start;
        const int dmax  = max(deg, __shfl_xor(deg, 32, 64));

        float acc[8] = {0.f, 0.f, 0.f, 0.f, 0.f, 0.f, 0.f, 0.f};

        for (int base = 0; base < dmax; base += 32) {
            int off = base + l32;
            int pe = (off < deg) ? csr[start + off] : Nn;  // sentinel: zero row
            int ecm = min(dmax - base, 32);
            int nkp = (ecm + 7) >> 3;

            for (int k = 0; k < nkp; ++k) {
                int j0 = g + 8 * k;
                int j1 = j0 + 4;
                int s0 = __shfl(pe, (lane & 32) + j0, 64);
                int s1 = __shfl(pe, (lane & 32) + j1, 64);
                H8 v0, v1;
                v0.i4 = ((const int4*)(Hh + (size_t)s0 * 64))[c];
                v1.i4 = ((const int4*)(Hh + (size_t)s1 * 64))[c];
#pragma unroll
                for (int t = 0; t < 4; ++t) {
                    H2U su;
                    su.h = __hadd2(v0.h2[t], v1.h2[t]);
                    fma_mix2(acc[2 * t], acc[2 * t + 1], su.u);
                }
            }
        }

#pragma unroll
        for (int m = 8; m <= 16; m <<= 1) {
#pragma unroll
            for (int k = 0; k < 8; ++k)
                acc[k] += __shfl_xor(acc[k], m, 64);
        }

        if (g == 0) {                           // 8 lanes per half -> LDS row
            float nm = nd[nodeC];
            float4 bb0 = ((const float4*)b)[2 * c];
            float4 bb1 = ((const float4*)b)[2 * c + 1];
            H8 o;
            o.h2[0] = __floats2half2_rn(fmaxf(fmaf(acc[0], nm, bb0.x), 0.f),
                                        fmaxf(fmaf(acc[1], nm, bb0.y), 0.f));
            o.h2[1] = __floats2half2_rn(fmaxf(fmaf(acc[2], nm, bb0.z), 0.f),
                                        fmaxf(fmaf(acc[3], nm, bb0.w), 0.f));
            o.h2[2] = __floats2half2_rn(fmaxf(fmaf(acc[4], nm, bb1.x), 0.f),
                                        fmaxf(fmaf(acc[5], nm, bb1.y), 0.f));
            o.h2[3] = __floats2half2_rn(fmaxf(fmaf(acc[6], nm, bb1.z), 0.f),
                                        fmaxf(fmaf(acc[7], nm, bb1.w), 0.f));
            *(int4*)(xt + nloc * KP + c * 8) = o.i4;
        }
    }
    __syncthreads();

    // ---- phase 2: gemm2, A from xt ----
    const int rowL = w * 16 + m16;

    floatx4 acc0 = {0.f, 0.f, 0.f, 0.f};
    floatx4 acc1 = acc0, acc2 = acc0, acc3 = acc0;

#pragma unroll
    for (int cc = 0; cc < K / 32; ++cc) {
        const int k0 = cc * 32 + quad * 8;
        half8 a = *(const half8*)&xt[rowL * KP + k0];
        half8 b0 = *(const half8*)&sWt[(0 * 16 + m16) * KP + k0];
        half8 b1 = *(const half8*)&sWt[(1 * 16 + m16) * KP + k0];
        half8 b2 = *(const half8*)&sWt[(2 * 16 + m16) * KP + k0];
        half8 b3 = *(const half8*)&sWt[(3 * 16 + m16) * KP + k0];
        acc0 = __builtin_amdgcn_mfma_f32_16x16x32_f16(a, b0, acc0, 0, 0, 0);
        acc1 = __builtin_amdgcn_mfma_f32_16x16x32_f16(a, b1, acc1, 0, 0, 0);
        acc2 = __builtin_amdgcn_mfma_f32_16x16x32_f16(a, b2, acc2, 0, 0, 0);
        acc3 = __builtin_amdgcn_mfma_f32_16x16x32_f16(a, b3, acc3, 0, 0, 0);
    }

    const int rbase = blockIdx.x * 64 + w * 16 + quad * 4;
    floatx4 accs[4] = {acc0, acc1, acc2, acc3};
#pragma unroll
    for (int i = 0; i < 4; ++i) {
        int grow = rbase + i;
        if (grow < Nn) {
            float nm = norm[grow];
            __half* o = Xout + (size_t)grow * 64 + m16;
#pragma unroll
            for (int t = 0; t < 4; ++t)
                o[16 * t] = (__half)(accs[t][i] * nm);
        } else if (grow == Nn) {               // sentinel zero row for gatherL2
            __half* o = Xout + (size_t)grow * 64 + m16;
#pragma unroll
            for (int t = 0; t < 4; ++t)
                o[16 * t] = (__half)0.f;
        }
    }
}

// ---------------- pull gather L2 + fused projection/softmax ----------------

__global__ void gather_proj_kernel(const int* __restrict__ starts, const int* __restrict__ ends,
                                   const int* __restrict__ csr, const __half* __restrict__ Hh,
                                   const float* __restrict__ nd, const float* __restrict__ b,
                                   const float* __restrict__ Wp, const float* __restrict__ bp,
                                   float* __restrict__ out, int Nn) {
    __shared__ float sW[NLAB * 65];     // [label][feat], pad 65
    __shared__ float sb_[NLAB];
    const int tid = threadIdx.x;

    for (int i = tid; i < 64 * NLAB; i += 256) {
        int k = i >> 3, l = i & 7;
        sW[l * 65 + k] = Wp[i];         // transpose: Wp is [feat][label]
    }
    if (tid < NLAB) sb_[tid] = bp[tid];
    __syncthreads();

    const int lane = tid & 63;
    const int half32 = (lane >> 5) & 1;
    const int l32 = lane & 31;
    const int g = l32 >> 3;
    const int c = lane & 7;

    int node = blockIdx.x * 8 + ((tid >> 6) << 1) + half32;
    const bool valid = node < Nn;
    const int nodeC = valid ? node : (Nn - 1);

    const int start = starts[nodeC];
    const int deg   = ends[nodeC] - start;
    const int dmax  = max(deg, __shfl_xor(deg, 32, 64));

    float acc[8] = {0.f, 0.f, 0.f, 0.f, 0.f, 0.f, 0.f, 0.f};

    for (int base = 0; base < dmax; base += 32) {
        int off = base + l32;
        int pe = (off < deg) ? csr[start + off] : Nn;  // sentinel: zero row
        int ecm = min(dmax - base, 32);
        int nkp = (ecm + 7) >> 3;

        for (int k = 0; k < nkp; ++k) {
            int j0 = g + 8 * k;
            int j1 = j0 + 4;
            int s0 = __shfl(pe, (lane & 32) + j0, 64);
            int s1 = __shfl(pe, (lane & 32) + j1, 64);
            H8 v0, v1;
            v0.i4 = ((const int4*)(Hh + (size_t)s0 * 64))[c];
            v1.i4 = ((const int4*)(Hh + (size_t)s1 * 64))[c];
#pragma unroll
            for (int t = 0; t < 4; ++t) {
                H2U su;
                su.h = __hadd2(v0.h2[t], v1.h2[t]);
                fma_mix2(acc[2 * t], acc[2 * t + 1], su.u);
            }
        }
    }

#pragma unroll
    for (int m = 8; m <= 16; m <<= 1) {
#pragma unroll
        for (int k = 0; k < 8; ++k)
            acc[k] += __shfl_xor(acc[k], m, 64);
    }

    // x row (fp32, un-rounded): feats 8c..8c+7, replicated across g
    float nm = nd[nodeC];
    float4 b0 = ((const float4*)b)[2 * c];
    float4 b1 = ((const float4*)b)[2 * c + 1];
    float xv[8];
    xv[0] = fmaxf(fmaf(acc[0], nm, b0.x), 0.f);
    xv[1] = fmaxf(fmaf(acc[1], nm, b0.y), 0.f);
    xv[2] = fmaxf(fmaf(acc[2], nm, b0.z), 0.f);
    xv[3] = fmaxf(fmaf(acc[3], nm, b0.w), 0.f);
    xv[4] = fmaxf(fmaf(acc[4], nm, b1.x), 0.f);
    xv[5] = fmaxf(fmaf(acc[5], nm, b1.y), 0.f);
    xv[6] = fmaxf(fmaf(acc[6], nm, b1.z), 0.f);
    xv[7] = fmaxf(fmaf(acc[7], nm, b1.w), 0.f);

    const int l0 = 2 * g, l1 = l0 + 1;
    float p0 = 0.f, p1 = 0.f;
#pragma unroll
    for (int j = 0; j < 8; ++j) {
        p0 = fmaf(xv[j], sW[l0 * 65 + 8 * c + j], p0);
        p1 = fmaf(xv[j], sW[l1 * 65 + 8 * c + j], p1);
    }
    p0 += __shfl_xor(p0, 1, 64); p1 += __shfl_xor(p1, 1, 64);
    p0 += __shfl_xor(p0, 2, 64); p1 += __shfl_xor(p1, 2, 64);
    p0 += __shfl_xor(p0, 4, 64); p1 += __shfl_xor(p1, 4, 64);
    p0 += sb_[l0];
    p1 += sb_[l1];
    float mx = fmaxf(p0, p1);
    mx = fmaxf(mx, __shfl_xor(mx, 8, 64));
    mx = fmaxf(mx, __shfl_xor(mx, 16, 64));
    float e0 = __expf(p0 - mx), e1 = __expf(p1 - mx);
    float s2 = e0 + e1;
    s2 += __shfl_xor(s2, 8, 64);
    s2 += __shfl_xor(s2, 16, 64);
    float inv = 1.0f / s2;
    if (c == 0 && valid) {
        float2 o = {e0 * inv, e1 * inv};
        *(float2*)(out + (size_t)node * NLAB + l0) = o;
    }
}

// ---------------- launch ----------------

extern "C" void kernel_launch(void* const* d_in, const int* in_sizes, int n_in,
                              void* d_out, int out_size, void* d_ws, size_t ws_size,
                              hipStream_t stream) {
    const float* features = (const float*)d_in[0];
    const int*   edge_src = (const int*)d_in[1];
    const int*   edge_dst = (const int*)d_in[2];
    const float* W1 = (const float*)d_in[4];
    const float* b1 = (const float*)d_in[5];
    const float* W2 = (const float*)d_in[6];
    const float* b2 = (const float*)d_in[7];
    const float* Wp = (const float*)d_in[8];
    const float* bp = (const float*)d_in[9];
    float* out = (float*)d_out;

    const int N = NODES;
    const int E = in_sizes[1];

    // ---- workspace layout (~35 MB) ----
    // h and x both have N+64 rows (row N = sentinel zero row). dreg/sreg
    // alias x (dead until gather_gemm writes x): csr2/shist consume them
    // strictly before, so build2's csr2 and gemm1 (writes h) are race-free.
    char* p = (char*)d_ws;
    int*   csr    = (int*)p;            p += sizeof(int) * (size_t)NHALF * CAPH;  // 7.2 MB
    int*   starts = (int*)p;            p += sizeof(int) * N;
    int*   ends   = (int*)p;            p += sizeof(int) * N;
    float* norm_s = (float*)p;          p += sizeof(float) * N;
    float* norm_d = (float*)p;          p += sizeof(float) * N;
    int*   gcur_d = (int*)p;            p += sizeof(int) * NHALF * GSTRIDE;  // zeroed
    int*   gcur_s = (int*)p;            p += sizeof(int) * NSB * GSTRIDE;    // zeroed
    p = (char*)(((size_t)p + 255) & ~(size_t)255);
    _Float16* wt1 = (_Float16*)p;       p += sizeof(_Float16) * 64 * (INF + 8);
    _Float16* wt2 = (_Float16*)p;       p += sizeof(_Float16) * 64 * (HID + 8);
    p = (char*)(((size_t)p + 255) & ~(size_t)255);
    __half* h     = (__half*)p;         p += sizeof(__half) * ((size_t)N + 64) * 64; // + sentinel
    p = (char*)(((size_t)p + 255) & ~(size_t)255);
    __half* x     = (__half*)p;         p += sizeof(__half) * ((size_t)N + 64) * 64; // + sentinel
    // aliases inside x (dead before gather_gemm writes x):
    int*            dreg = (int*)x;                                              // 7.19 MB
    unsigned short* sreg = (unsigned short*)((char*)x + sizeof(int) * (size_t)NHALF * CAPH); // 3.5 MB

    hipMemsetAsync(gcur_d, 0, sizeof(int) * (NHALF + NSB) * GSTRIDE, stream);

    // ---- build: [partition || wcvt] -> shist -> [CSR || gemm1] ----
    const int partWGs = (E + PCHUNK - 1) / PCHUNK;
    build1_kernel<<<partWGs + WCVT_WGS, B1T, 0, stream>>>(edge_src, edge_dst,
                                                          gcur_d, gcur_s, dreg, sreg,
                                                          E, partWGs, W1, W2, wt1, wt2);
    shist_kernel<<<NSB, 256, 0, stream>>>(sreg, gcur_s, norm_s, N);
    build2_kernel<<<NHALF + (N + 63) / 64, 256, 0, stream>>>(dreg, gcur_d, csr, starts,
                                                             ends, norm_d,
                                                             features, norm_s, wt1, h, N);

    // ---- fused: gatherL1 (h -> LDS tile) + gemm2 (-> x, sentinel) ----
    gather_gemm_kernel<<<(N + 63) / 64, 256, 0, stream>>>(starts, ends, csr, h, norm_d,
                                                          b1, norm_s, wt2, x, N);

    // ---- gatherL2 + projection + softmax ----
    gather_proj_kernel<<<(N + 7) / 8, 256, 0, stream>>>(starts, ends, csr, x, norm_d,
                                                        b2, Wp, bp, out, N);
}

// Round 12
// 218.766 us; speedup vs baseline: 1.1083x; 1.0436x over previous
//
#include <hip/hip_runtime.h>
#include <hip/hip_fp16.h>
#include <math.h>

// GCN: 2x GraphConv(norm='both') + projection + softmax.
// N=100000 nodes, E=1600000 edges, feats 128 -> 64 -> 64 -> 8. All fp32 I/O.
//
// R24 = R23 resubmitted (container infra failed twice last round; kernel
// re-audited: norm_s bounds/sentinel OK, build2 3-way split race-free).
// R23 (on R22 = 228.3us): norm_s scaling moved from the GEMM epilogues to a
// per-edge scale in the gathers (agg = sum norm_s[src]*h[src], h=fp16(XW)
// unscaled). This frees build2 from the norm_s dependency, so shist's 196
// blocks FUSE into build2's dispatch (shist || csr2 || gemm1): one fewer
// serial dispatch. Gather cost: +2 broadcast norm_s loads + 4 VALU per 2
// edges -- free, gather is memory-bound not VALU-bound (R20 null). Numerics:
// the fp16 pair-add rounding is REMOVED (all post-rounding math fp32) ->
// strictly fewer roundings. norm_s[N] (sentinel) = 1.0 via shist's empty bin.

#define NODES   100000
#define INF     128
#define HID     64
#define NLAB    8

#define SB      512                         // nodes per src super-bucket
#define NSB     ((NODES + SB - 1) / SB)     // 196 (src side)
#define NHALF   ((NODES + 255) / 256)       // 391 dst half-buckets (256 nodes)
#define SCAP    9000                        // per-sb src cap
#define CAPH    4600                        // per-half edge cap (mean 4096, sigma~64)
#define PCHUNK  8192                        // edges per part WG (196 blocks)
#define B1T     1024                        // build1 threads per block
#define PEPT    (PCHUNK / B1T)              // 8
#define SRCMASK 0x1FFFF                     // 17 bits
#define GSTRIDE 16                          // ints; one gcur counter per 64B line

#define WCVT_ELEMS (64 * (INF + 8) + 64 * (HID + 8))
#define WCVT_WGS   ((WCVT_ELEMS + B1T - 1) / B1T)

union H8 { int4 i4; __half2 h2[4]; unsigned int u[4]; };

typedef _Float16 half8 __attribute__((ext_vector_type(8)));
typedef float floatx4 __attribute__((ext_vector_type(4)));

// acc0 += (float)lo16(h2) * s; acc1 += (float)hi16(h2) * s — VOP3P mix-FMA.
// Exact f16->f32 convert inside the FMA; scale/accumulate in fp32.
__device__ __forceinline__ void fma_mixs2(float& a0, float& a1, unsigned int h2, float s) {
    asm("v_fma_mix_f32 %0, %2, %3, %0 op_sel_hi:[1,0,0]\n\t"
        "v_fma_mix_f32 %1, %2, %3, %1 op_sel:[1,0,0] op_sel_hi:[1,0,0]"
        : "+v"(a0), "+v"(a1) : "v"(h2), "v"(s));
}

// ---------------- build1: partition edges by dst>>8; src vals by src>>9 ----------------
// 1024 threads/block (+ W convert in trailing blocks)

__global__ __launch_bounds__(B1T)
void build1_kernel(const int* __restrict__ src, const int* __restrict__ dst,
                   int* __restrict__ gcur_d, int* __restrict__ gcur_s,
                   int* __restrict__ dreg, unsigned short* __restrict__ sreg,
                   int E, int partWGs,
                   const float* __restrict__ W1, const float* __restrict__ W2,
                   _Float16* __restrict__ wt1, _Float16* __restrict__ wt2) {
    __shared__ int hd[NHALF], bd[NHALF], hs[NSB], bs[NSB];
    const int tid = threadIdx.x;

    if (blockIdx.x >= partWGs) {
        // ---- W convert: fp32 [K][64] -> fp16 transposed [64][K+8] ----
        const int N1 = 64 * (INF + 8);
        const int N2 = 64 * (HID + 8);
        int i = (blockIdx.x - partWGs) * B1T + tid;
        if (i < N1) {
            int n = i / (INF + 8), k = i % (INF + 8);
            wt1[i] = (k < INF) ? (_Float16)W1[k * 64 + n] : (_Float16)0.f;
        } else if (i < N1 + N2) {
            int j = i - N1;
            int n = j / (HID + 8), k = j % (HID + 8);
            wt2[j] = (k < HID) ? (_Float16)W2[k * 64 + n] : (_Float16)0.f;
        }
        return;
    }

    const int e0 = blockIdx.x * PCHUNK;

    for (int i = tid; i < NHALF; i += B1T) { hd[i] = 0; }
    for (int i = tid; i < NSB; i += B1T) { hs[i] = 0; }
    __syncthreads();

    // phase A: LDS histograms (edges re-read from L2 in phase C)
    int es[PEPT], ed[PEPT];
#pragma unroll
    for (int i = 0; i < PEPT; ++i) {
        int e = e0 + tid + i * B1T;
        if (e < E) {
            es[i] = src[e]; ed[i] = dst[e];
            atomicAdd(&hd[ed[i] >> 8], 1);
            atomicAdd(&hs[es[i] >> 9], 1);
        } else es[i] = -1;
    }
    __syncthreads();

    // phase B: reserve contiguous runs (chain depth = 196 blocks;
    // line-spread counters -> 587 chains drain in parallel; one round)
    if (tid < NHALF) {
        int c = hd[tid]; bd[tid] = c ? atomicAdd(&gcur_d[tid * GSTRIDE], c) : 0;
    }
    if (tid < NSB) {
        int c = hs[tid]; bs[tid] = c ? atomicAdd(&gcur_s[tid * GSTRIDE], c) : 0;
    }
    __syncthreads();
    for (int b = tid; b < NHALF; b += B1T) hd[b] = 0;
    for (int b = tid; b < NSB; b += B1T) hs[b] = 0;
    __syncthreads();

    // phase C: scatter into runs (dst_local(8b)<<17 | src; src_local as ushort)
#pragma unroll
    for (int i = 0; i < PEPT; ++i) {
        if (es[i] >= 0) {
            int s = es[i], d = ed[i];
            int kb = d >> 8;
            int pos = bd[kb] + atomicAdd(&hd[kb], 1);
            if (pos < CAPH) dreg[(size_t)kb * CAPH + pos] = ((d & 255) << 17) | s;
            int ks = s >> 9;
            int ps = bs[ks] + atomicAdd(&hs[ks], 1);
            if (ps < SCAP) sreg[(size_t)ks * SCAP + ps] = (unsigned short)(s & (SB - 1));
        }
    }
}

// ---------------- build2: shist || csr2 || gemm1, one dispatch ----------------
// Blocks [0, NSB): shist (src-degree histogram -> norm_s; bin Nn empty -> 1.0).
// Blocks [NSB, NSB+NHALF): csr2 per-half-bucket counting sort -> CSR + norm_d.
// Rest: gemm1 Hh = fp16(X@W1) (UNSCALED; norm_s applied per-edge in gather);
// row Nn (sentinel) = 0. All three independent (gemm1 no longer reads norm_s).

__global__ void build2_kernel(const int* __restrict__ dreg, const int* __restrict__ gcur_d,
                              int* __restrict__ csr, int* __restrict__ starts,
                              int* __restrict__ ends, float* __restrict__ norm_d,
                              const float* __restrict__ Xv,
                              const _Float16* __restrict__ Wt, __half* __restrict__ Hh,
                              const unsigned short* __restrict__ sreg,
                              const int* __restrict__ gcur_s, float* __restrict__ norm_s,
                              int Nn) {
    __shared__ union SMem {
        int sh[SB];
        struct CS { int hist[256]; int cur[256]; int wsum[4]; int sorted[CAPH]; } c;
        _Float16 w[64 * (INF + 8)];
    } sm;
    const int tid = threadIdx.x;

    if (blockIdx.x < NSB) {
        // ---- shist: src-degree histogram per super-bucket -> norm_s ----
        const int sb = blockIdx.x;
        for (int i = tid; i < SB; i += 256) sm.sh[i] = 0;
        __syncthreads();
        const int cnt = min(gcur_s[sb * GSTRIDE], SCAP);
        const unsigned short* base = sreg + (size_t)sb * SCAP;
        for (int i = tid; i < cnt; i += 256) atomicAdd(&sm.sh[base[i]], 1);
        __syncthreads();
        for (int t = tid; t < SB; t += 256) {
            int node = sb * SB + t;
            if (node <= Nn)     // node == Nn: empty bin -> 1.0 (sentinel scale)
                norm_s[node] = rsqrtf(fmaxf((float)sm.sh[t], 1.0f));
        }
        return;
    }

    if (blockIdx.x < NSB + NHALF) {
        // ---- csr2: WG j owns nodes [j*256, j*256+256) = dst bucket j ----
        const int j = blockIdx.x - NSB;
        const int cnt = min(gcur_d[j * GSTRIDE], CAPH);
        const int* reg = dreg + (size_t)j * CAPH;

        sm.c.hist[tid] = 0;
        __syncthreads();

        for (int i = tid; i < cnt; i += 256)
            atomicAdd(&sm.c.hist[(reg[i] >> 17) & 255], 1);
        __syncthreads();

        // exclusive scan over 256: wave shfl_up scan + 4-word combine
        const int lane = tid & 63, wid = tid >> 6;
        int deg_n = sm.c.hist[tid];
        int v = deg_n;
#pragma unroll
        for (int off = 1; off < 64; off <<= 1) {
            int u = __shfl_up(v, off, 64);
            if (lane >= off) v += u;
        }
        if (lane == 63) sm.c.wsum[wid] = v;
        __syncthreads();
        int wadd = 0;
#pragma unroll
        for (int q = 0; q < 3; ++q) wadd += (q < wid) ? sm.c.wsum[q] : 0;
        int st = v + wadd - deg_n;

        int node = j * 256 + tid;
        if (node < Nn) {
            int gs = j * CAPH + st;
            int dcl = min(deg_n, max(CAPH - st, 0));
            starts[node] = gs;
            ends[node]   = gs + dcl;
            norm_d[node] = rsqrtf(fmaxf((float)deg_n, 1.0f));
        }
        sm.c.cur[tid] = st;
        __syncthreads();

        for (int i = tid; i < cnt; i += 256) {
            int pe = reg[i];
            int pos = atomicAdd(&sm.c.cur[(pe >> 17) & 255], 1);
            if (pos < CAPH) sm.c.sorted[pos] = pe & SRCMASK;
        }
        __syncthreads();

        for (int i = tid; i < cnt; i += 256) csr[(size_t)j * CAPH + i] = sm.c.sorted[i];
        return;
    }

    // ---- gemm1: block = 64 rows, 4 waves x 16; K=128 fp32 input ----
    constexpr int K = INF;
    constexpr int KP = K + 8;
    const int bid = blockIdx.x - NSB - NHALF;

    constexpr int NI4 = 64 * KP * 2 / 16;
    for (int i = tid; i < NI4; i += 256)
        ((int4*)sm.w)[i] = ((const int4*)Wt)[i];
    __syncthreads();

    const int w = tid >> 6, lane = tid & 63;
    const int m16 = lane & 15, quad = lane >> 4;
    const int rowA = bid * 64 + w * 16 + m16;
    const int rowC = (rowA < Nn) ? rowA : (Nn - 1);

    floatx4 acc0 = {0.f, 0.f, 0.f, 0.f};
    floatx4 acc1 = acc0, acc2 = acc0, acc3 = acc0;

#pragma unroll
    for (int c = 0; c < K / 32; ++c) {
        const int k0 = c * 32 + quad * 8;
        const float* xrow = Xv + (size_t)rowC * K;
        float4 xa = *(const float4*)(xrow + k0);
        float4 xb = *(const float4*)(xrow + k0 + 4);
        half8 a;
        a[0] = (_Float16)xa.x; a[1] = (_Float16)xa.y;
        a[2] = (_Float16)xa.z; a[3] = (_Float16)xa.w;
        a[4] = (_Float16)xb.x; a[5] = (_Float16)xb.y;
        a[6] = (_Float16)xb.z; a[7] = (_Float16)xb.w;
        half8 b0 = *(const half8*)&sm.w[(0 * 16 + m16) * KP + k0];
        half8 b1 = *(const half8*)&sm.w[(1 * 16 + m16) * KP + k0];
        half8 b2 = *(const half8*)&sm.w[(2 * 16 + m16) * KP + k0];
        half8 b3 = *(const half8*)&sm.w[(3 * 16 + m16) * KP + k0];
        acc0 = __builtin_amdgcn_mfma_f32_16x16x32_f16(a, b0, acc0, 0, 0, 0);
        acc1 = __builtin_amdgcn_mfma_f32_16x16x32_f16(a, b1, acc1, 0, 0, 0);
        acc2 = __builtin_amdgcn_mfma_f32_16x16x32_f16(a, b2, acc2, 0, 0, 0);
        acc3 = __builtin_amdgcn_mfma_f32_16x16x32_f16(a, b3, acc3, 0, 0, 0);
    }

    const int rbase = bid * 64 + w * 16 + quad * 4;
    floatx4 accs[4] = {acc0, acc1, acc2, acc3};
#pragma unroll
    for (int i = 0; i < 4; ++i) {
        int grow = rbase + i;
        if (grow < Nn) {
            __half* o = Hh + (size_t)grow * 64 + m16;
#pragma unroll
            for (int t = 0; t < 4; ++t)
                o[16 * t] = (__half)accs[t][i];
        } else if (grow == Nn) {               // sentinel zero row for gather
            __half* o = Hh + (size_t)grow * 64 + m16;
#pragma unroll
            for (int t = 0; t < 4; ++t)
                o[16 * t] = (__half)0.f;
        }
    }
}

// ---------------- fused gatherL1 + gemm2: block = 64 nodes ----------------
// Phase 1: 2-node-per-wave pull gather with PER-EDGE norm_s scale
// (acc += ns[src] * h[src], fp32), epilogue writes relu(nd*acc + b1) fp16
// into LDS tile xt[64][72]. Phase 2: K=64 MFMA GEMM, A-frags from xt,
// output fp16(xt@W2) UNSCALED -> Xout (sentinel row Nn = 0).

__global__ void gather_gemm_kernel(const int* __restrict__ starts, const int* __restrict__ ends,
                                   const int* __restrict__ csr, const __half* __restrict__ Hh,
                                   const float* __restrict__ nd, const float* __restrict__ b,
                                   const float* __restrict__ ns, const _Float16* __restrict__ Wt,
                                   __half* __restrict__ Xout, int Nn) {
    constexpr int K = HID;
    constexpr int KP = K + 8;
    __shared__ _Float16 sWt[64 * KP];   // 9.2 KB
    __shared__ _Float16 xt[64 * KP];    // 9.2 KB x-tile

    const int tid = threadIdx.x;
    constexpr int NI4 = 64 * KP * 2 / 16;
    for (int i = tid; i < NI4; i += 256)
        ((int4*)sWt)[i] = ((const int4*)Wt)[i];
    // (barrier below covers sWt before phase 2 use)

    const int lane = tid & 63;
    const int half32 = (lane >> 5) & 1;         // node slot within wave
    const int l32 = lane & 31;                  // lane within half
    const int g = l32 >> 3;                     // edge slot group 0..3
    const int c = lane & 7;                     // 16B col chunk
    const int w = tid >> 6;
    const int m16 = lane & 15, quad = lane >> 4;

    // ---- phase 1: gather 16 nodes per wave (2 per iteration) ----
#pragma unroll 1
    for (int it = 0; it < 8; ++it) {
        const int nloc = w * 16 + it * 2 + half32;       // 0..63
        const int node = blockIdx.x * 64 + nloc;
        const int nodeC = (node < Nn) ? node : (Nn - 1);

        const int start = starts[nodeC];
        const int deg   = ends[nodeC] - start;
        const int dmax  = max(deg, __shfl_xor(deg, 32, 64));

        float acc[8] = {0.f, 0.f, 0.f, 0.f, 0.f, 0.f, 0.f, 0.f};

        for (int base = 0; base < dmax; base += 32) {
            int off = base + l32;
            int pe = (off < deg) ? csr[start + off] : Nn;  // sentinel: zero row
            int ecm = min(dmax - base, 32);
            int nkp = (ecm + 7) >> 3;

            for (int k = 0; k < nkp; ++k) {
                int j0 = g + 8 * k;
                int j1 = j0 + 4;
                int s0 = __shfl(pe, (lane & 32) + j0, 64);
                int s1 = __shfl(pe, (lane & 32) + j1, 64);
                float n0 = ns[s0], n1 = ns[s1];            // broadcast in group
                H8 v0, v1;
                v0.i4 = ((const int4*)(Hh + (size_t)s0 * 64))[c];
                v1.i4 = ((const int4*)(Hh + (size_t)s1 * 64))[c];
#pragma unroll
                for (int t = 0; t < 4; ++t) {
                    fma_mixs2(acc[2 * t], acc[2 * t + 1], v0.u[t], n0);
                    fma_mixs2(acc[2 * t], acc[2 * t + 1], v1.u[t], n1);
                }
            }
        }

#pragma unroll
        for (int m = 8; m <= 16; m <<= 1) {
#pragma unroll
            for (int k = 0; k < 8; ++k)
                acc[k] += __shfl_xor(acc[k], m, 64);
        }

        if (g == 0) {                           // 8 lanes per half -> LDS row
            float nm = nd[nodeC];
            float4 bb0 = ((const float4*)b)[2 * c];
            float4 bb1 = ((const float4*)b)[2 * c + 1];
            H8 o;
            o.h2[0] = __floats2half2_rn(fmaxf(fmaf(acc[0], nm, bb0.x), 0.f),
                                        fmaxf(fmaf(acc[1], nm, bb0.y), 0.f));
            o.h2[1] = __floats2half2_rn(fmaxf(fmaf(acc[2], nm, bb0.z), 0.f),
                                        fmaxf(fmaf(acc[3], nm, bb0.w), 0.f));
            o.h2[2] = __floats2half2_rn(fmaxf(fmaf(acc[4], nm, bb1.x), 0.f),
                                        fmaxf(fmaf(acc[5], nm, bb1.y), 0.f));
            o.h2[3] = __floats2half2_rn(fmaxf(fmaf(acc[6], nm, bb1.z), 0.f),
                                        fmaxf(fmaf(acc[7], nm, bb1.w), 0.f));
            *(int4*)(xt + nloc * KP + c * 8) = o.i4;
        }
    }
    __syncthreads();

    // ---- phase 2: gemm2, A from xt ----
    const int rowL = w * 16 + m16;

    floatx4 acc0 = {0.f, 0.f, 0.f, 0.f};
    floatx4 acc1 = acc0, acc2 = acc0, acc3 = acc0;

#pragma unroll
    for (int cc = 0; cc < K / 32; ++cc) {
        const int k0 = cc * 32 + quad * 8;
        half8 a = *(const half8*)&xt[rowL * KP + k0];
        half8 b0 = *(const half8*)&sWt[(0 * 16 + m16) * KP + k0];
        half8 b1 = *(const half8*)&sWt[(1 * 16 + m16) * KP + k0];
        half8 b2 = *(const half8*)&sWt[(2 * 16 + m16) * KP + k0];
        half8 b3 = *(const half8*)&sWt[(3 * 16 + m16) * KP + k0];
        acc0 = __builtin_amdgcn_mfma_f32_16x16x32_f16(a, b0, acc0, 0, 0, 0);
        acc1 = __builtin_amdgcn_mfma_f32_16x16x32_f16(a, b1, acc1, 0, 0, 0);
        acc2 = __builtin_amdgcn_mfma_f32_16x16x32_f16(a, b2, acc2, 0, 0, 0);
        acc3 = __builtin_amdgcn_mfma_f32_16x16x32_f16(a, b3, acc3, 0, 0, 0);
    }

    const int rbase = blockIdx.x * 64 + w * 16 + quad * 4;
    floatx4 accs[4] = {acc0, acc1, acc2, acc3};
#pragma unroll
    for (int i = 0; i < 4; ++i) {
        int grow = rbase + i;
        if (grow < Nn) {
            __half* o = Xout + (size_t)grow * 64 + m16;
#pragma unroll
            for (int t = 0; t < 4; ++t)
                o[16 * t] = (__half)accs[t][i];
        } else if (grow == Nn) {               // sentinel zero row for gatherL2
            __half* o = Xout + (size_t)grow * 64 + m16;
#pragma unroll
            for (int t = 0; t < 4; ++t)
                o[16 * t] = (__half)0.f;
        }
    }
}

// ---------------- pull gather L2 + fused projection/softmax ----------------
// Per-edge norm_s scale; sentinel tail slots. Epilogue: x@Wp + bp + softmax
// in-register (labels 2/g-group, LDS Wp transposed pad-65, butterflies over
// c then g; c==0 lanes store float2).

__global__ void gather_proj_kernel(const int* __restrict__ starts, const int* __restrict__ ends,
                                   const int* __restrict__ csr, const __half* __restrict__ Hh,
                                   const float* __restrict__ nd, const float* __restrict__ b,
                                   const float* __restrict__ ns,
                                   const float* __restrict__ Wp, const float* __restrict__ bp,
                                   float* __restrict__ out, int Nn) {
    __shared__ float sW[NLAB * 65];     // [label][feat], pad 65
    __shared__ float sb_[NLAB];
    const int tid = threadIdx.x;

    for (int i = tid; i < 64 * NLAB; i += 256) {
        int k = i >> 3, l = i & 7;
        sW[l * 65 + k] = Wp[i];         // transpose: Wp is [feat][label]
    }
    if (tid < NLAB) sb_[tid] = bp[tid];
    __syncthreads();

    const int lane = tid & 63;
    const int half32 = (lane >> 5) & 1;
    const int l32 = lane & 31;
    const int g = l32 >> 3;
    const int c = lane & 7;

    int node = blockIdx.x * 8 + ((tid >> 6) << 1) + half32;
    const bool valid = node < Nn;
    const int nodeC = valid ? node : (Nn - 1);

    const int start = starts[nodeC];
    const int deg   = ends[nodeC] - start;
    const int dmax  = max(deg, __shfl_xor(deg, 32, 64));

    float acc[8] = {0.f, 0.f, 0.f, 0.f, 0.f, 0.f, 0.f, 0.f};

    for (int base = 0; base < dmax; base += 32) {
        int off = base + l32;
        int pe = (off < deg) ? csr[start + off] : Nn;  // sentinel: zero row
        int ecm = min(dmax - base, 32);
        int nkp = (ecm + 7) >> 3;

        for (int k = 0; k < nkp; ++k) {
            int j0 = g + 8 * k;
            int j1 = j0 + 4;
            int s0 = __shfl(pe, (lane & 32) + j0, 64);
            int s1 = __shfl(pe, (lane & 32) + j1, 64);
            float n0 = ns[s0], n1 = ns[s1];            // broadcast in group
            H8 v0, v1;
            v0.i4 = ((const int4*)(Hh + (size_t)s0 * 64))[c];
            v1.i4 = ((const int4*)(Hh + (size_t)s1 * 64))[c];
#pragma unroll
            for (int t = 0; t < 4; ++t) {
                fma_mixs2(acc[2 * t], acc[2 * t + 1], v0.u[t], n0);
                fma_mixs2(acc[2 * t], acc[2 * t + 1], v1.u[t], n1);
            }
        }
    }

#pragma unroll
    for (int m = 8; m <= 16; m <<= 1) {
#pragma unroll
        for (int k = 0; k < 8; ++k)
            acc[k] += __shfl_xor(acc[k], m, 64);
    }

    // x row (fp32, un-rounded): feats 8c..8c+7, replicated across g
    float nm = nd[nodeC];
    float4 b0 = ((const float4*)b)[2 * c];
    float4 b1 = ((const float4*)b)[2 * c + 1];
    float xv[8];
    xv[0] = fmaxf(fmaf(acc[0], nm, b0.x), 0.f);
    xv[1] = fmaxf(fmaf(acc[1], nm, b0.y), 0.f);
    xv[2] = fmaxf(fmaf(acc[2], nm, b0.z), 0.f);
    xv[3] = fmaxf(fmaf(acc[3], nm, b0.w), 0.f);
    xv[4] = fmaxf(fmaf(acc[4], nm, b1.x), 0.f);
    xv[5] = fmaxf(fmaf(acc[5], nm, b1.y), 0.f);
    xv[6] = fmaxf(fmaf(acc[6], nm, b1.z), 0.f);
    xv[7] = fmaxf(fmaf(acc[7], nm, b1.w), 0.f);

    const int l0 = 2 * g, l1 = l0 + 1;
    float p0 = 0.f, p1 = 0.f;
#pragma unroll
    for (int j = 0; j < 8; ++j) {
        p0 = fmaf(xv[j], sW[l0 * 65 + 8 * c + j], p0);
        p1 = fmaf(xv[j], sW[l1 * 65 + 8 * c + j], p1);
    }
    p0 += __shfl_xor(p0, 1, 64); p1 += __shfl_xor(p1, 1, 64);
    p0 += __shfl_xor(p0, 2, 64); p1 += __shfl_xor(p1, 2, 64);
    p0 += __shfl_xor(p0, 4, 64); p1 += __shfl_xor(p1, 4, 64);
    p0 += sb_[l0];
    p1 += sb_[l1];
    float mx = fmaxf(p0, p1);
    mx = fmaxf(mx, __shfl_xor(mx, 8, 64));
    mx = fmaxf(mx, __shfl_xor(mx, 16, 64));
    float e0 = __expf(p0 - mx), e1 = __expf(p1 - mx);
    float s2 = e0 + e1;
    s2 += __shfl_xor(s2, 8, 64);
    s2 += __shfl_xor(s2, 16, 64);
    float inv = 1.0f / s2;
    if (c == 0 && valid) {
        float2 o = {e0 * inv, e1 * inv};
        *(float2*)(out + (size_t)node * NLAB + l0) = o;
    }
}

// ---------------- launch ----------------

extern "C" void kernel_launch(void* const* d_in, const int* in_sizes, int n_in,
                              void* d_out, int out_size, void* d_ws, size_t ws_size,
                              hipStream_t stream) {
    const float* features = (const float*)d_in[0];
    const int*   edge_src = (const int*)d_in[1];
    const int*   edge_dst = (const int*)d_in[2];
    const float* W1 = (const float*)d_in[4];
    const float* b1 = (const float*)d_in[5];
    const float* W2 = (const float*)d_in[6];
    const float* b2 = (const float*)d_in[7];
    const float* Wp = (const float*)d_in[8];
    const float* bp = (const float*)d_in[9];
    float* out = (float*)d_out;

    const int N = NODES;
    const int E = in_sizes[1];

    // ---- workspace layout (~35 MB) ----
    // h and x both have N+64 rows (row N = sentinel zero row). norm_s has
    // N+16 entries (entry N = 1.0 sentinel scale). dreg/sreg alias x (dead
    // until gather_gemm writes x): shist/csr2 consume them strictly before.
    char* p = (char*)d_ws;
    int*   csr    = (int*)p;            p += sizeof(int) * (size_t)NHALF * CAPH;  // 7.2 MB
    int*   starts = (int*)p;            p += sizeof(int) * N;
    int*   ends   = (int*)p;            p += sizeof(int) * N;
    float* norm_s = (float*)p;          p += sizeof(float) * (N + 16);
    float* norm_d = (float*)p;          p += sizeof(float) * N;
    int*   gcur_d = (int*)p;            p += sizeof(int) * NHALF * GSTRIDE;  // zeroed
    int*   gcur_s = (int*)p;            p += sizeof(int) * NSB * GSTRIDE;    // zeroed
    p = (char*)(((size_t)p + 255) & ~(size_t)255);
    _Float16* wt1 = (_Float16*)p;       p += sizeof(_Float16) * 64 * (INF + 8);
    _Float16* wt2 = (_Float16*)p;       p += sizeof(_Float16) * 64 * (HID + 8);
    p = (char*)(((size_t)p + 255) & ~(size_t)255);
    __half* h     = (__half*)p;         p += sizeof(__half) * ((size_t)N + 64) * 64; // + sentinel
    p = (char*)(((size_t)p + 255) & ~(size_t)255);
    __half* x     = (__half*)p;         p += sizeof(__half) * ((size_t)N + 64) * 64; // + sentinel
    // aliases inside x (dead before gather_gemm writes x):
    int*            dreg = (int*)x;                                              // 7.19 MB
    unsigned short* sreg = (unsigned short*)((char*)x + sizeof(int) * (size_t)NHALF * CAPH); // 3.5 MB

    hipMemsetAsync(gcur_d, 0, sizeof(int) * (NHALF + NSB) * GSTRIDE, stream);

    // ---- build: [partition || wcvt] -> [shist || CSR || gemm1] ----
    const int partWGs = (E + PCHUNK - 1) / PCHUNK;
    build1_kernel<<<partWGs + WCVT_WGS, B1T, 0, stream>>>(edge_src, edge_dst,
                                                          gcur_d, gcur_s, dreg, sreg,
                                                          E, partWGs, W1, W2, wt1, wt2);
    build2_kernel<<<NSB + NHALF + (N + 63) / 64, 256, 0, stream>>>(dreg, gcur_d, csr,
                                                                   starts, ends, norm_d,
                                                                   features, wt1, h,
                                                                   sreg, gcur_s, norm_s, N);

    // ---- fused: gatherL1 (per-edge ns scale, h -> LDS tile) + gemm2 (-> x) ----
    gather_gemm_kernel<<<(N + 63) / 64, 256, 0, stream>>>(starts, ends, csr, h, norm_d,
                                                          b1, norm_s, wt2, x, N);

    // ---- gatherL2 (per-edge ns scale) + projection + softmax ----
    gather_proj_kernel<<<(N + 7) / 8, 256, 0, stream>>>(starts, ends, csr, x, norm_d,
                                                        b2, norm_s, Wp, bp, out, N);
}

// Round 13
// 217.966 us; speedup vs baseline: 1.1124x; 1.0037x over previous
//
#include <hip/hip_runtime.h>
#include <hip/hip_fp16.h>
#include <math.h>

// GCN: 2x GraphConv(norm='both') + projection + softmax.
// N=100000 nodes, E=1600000 edges, feats 128 -> 64 -> 64 -> 8. All fp32 I/O.
//
// R25 (on R24 = 218.8us): budget analysis says build2 is the hidden long
// pole (~55us): csr2's 391 + shist's 196 blocks at 256 threads = ~1.5
// blocks/CU = 1-2 waves/SIMD, same latency-starvation disease R22 fixed in
// build1. build2 -> 1024 threads: shist 4x fewer rounds, csr2 hist/scatter
// 16+16 -> 4+4 rounds (scan stays on first 256 threads = 4 full waves),
// gemm1 256 rows/block (16 waves share the W-tile). Grid 978 x 16 waves =
// ~2 blocks/CU = full occupancy. No numeric change. Everything else R24.

#define NODES   100000
#define INF     128
#define HID     64
#define NLAB    8

#define SB      512                         // nodes per src super-bucket
#define NSB     ((NODES + SB - 1) / SB)     // 196 (src side)
#define NHALF   ((NODES + 255) / 256)       // 391 dst half-buckets (256 nodes)
#define SCAP    9000                        // per-sb src cap
#define CAPH    4600                        // per-half edge cap (mean 4096, sigma~64)
#define PCHUNK  8192                        // edges per part WG (196 blocks)
#define B1T     1024                        // build1 threads per block
#define B2T     1024                        // build2 threads per block
#define PEPT    (PCHUNK / B1T)              // 8
#define SRCMASK 0x1FFFF                     // 17 bits
#define GSTRIDE 16                          // ints; one gcur counter per 64B line

#define WCVT_ELEMS (64 * (INF + 8) + 64 * (HID + 8))
#define WCVT_WGS   ((WCVT_ELEMS + B1T - 1) / B1T)

union H8 { int4 i4; __half2 h2[4]; unsigned int u[4]; };

typedef _Float16 half8 __attribute__((ext_vector_type(8)));
typedef float floatx4 __attribute__((ext_vector_type(4)));

// acc0 += (float)lo16(h2) * s; acc1 += (float)hi16(h2) * s — VOP3P mix-FMA.
// Exact f16->f32 convert inside the FMA; scale/accumulate in fp32.
__device__ __forceinline__ void fma_mixs2(float& a0, float& a1, unsigned int h2, float s) {
    asm("v_fma_mix_f32 %0, %2, %3, %0 op_sel_hi:[1,0,0]\n\t"
        "v_fma_mix_f32 %1, %2, %3, %1 op_sel:[1,0,0] op_sel_hi:[1,0,0]"
        : "+v"(a0), "+v"(a1) : "v"(h2), "v"(s));
}

// ---------------- build1: partition edges by dst>>8; src vals by src>>9 ----------------
// 1024 threads/block (+ W convert in trailing blocks)

__global__ __launch_bounds__(B1T)
void build1_kernel(const int* __restrict__ src, const int* __restrict__ dst,
                   int* __restrict__ gcur_d, int* __restrict__ gcur_s,
                   int* __restrict__ dreg, unsigned short* __restrict__ sreg,
                   int E, int partWGs,
                   const float* __restrict__ W1, const float* __restrict__ W2,
                   _Float16* __restrict__ wt1, _Float16* __restrict__ wt2) {
    __shared__ int hd[NHALF], bd[NHALF], hs[NSB], bs[NSB];
    const int tid = threadIdx.x;

    if (blockIdx.x >= partWGs) {
        // ---- W convert: fp32 [K][64] -> fp16 transposed [64][K+8] ----
        const int N1 = 64 * (INF + 8);
        const int N2 = 64 * (HID + 8);
        int i = (blockIdx.x - partWGs) * B1T + tid;
        if (i < N1) {
            int n = i / (INF + 8), k = i % (INF + 8);
            wt1[i] = (k < INF) ? (_Float16)W1[k * 64 + n] : (_Float16)0.f;
        } else if (i < N1 + N2) {
            int j = i - N1;
            int n = j / (HID + 8), k = j % (HID + 8);
            wt2[j] = (k < HID) ? (_Float16)W2[k * 64 + n] : (_Float16)0.f;
        }
        return;
    }

    const int e0 = blockIdx.x * PCHUNK;

    for (int i = tid; i < NHALF; i += B1T) { hd[i] = 0; }
    for (int i = tid; i < NSB; i += B1T) { hs[i] = 0; }
    __syncthreads();

    // phase A: LDS histograms (edges re-read from L2 in phase C)
    int es[PEPT], ed[PEPT];
#pragma unroll
    for (int i = 0; i < PEPT; ++i) {
        int e = e0 + tid + i * B1T;
        if (e < E) {
            es[i] = src[e]; ed[i] = dst[e];
            atomicAdd(&hd[ed[i] >> 8], 1);
            atomicAdd(&hs[es[i] >> 9], 1);
        } else es[i] = -1;
    }
    __syncthreads();

    // phase B: reserve contiguous runs (chain depth = 196 blocks;
    // line-spread counters -> 587 chains drain in parallel; one round)
    if (tid < NHALF) {
        int c = hd[tid]; bd[tid] = c ? atomicAdd(&gcur_d[tid * GSTRIDE], c) : 0;
    }
    if (tid < NSB) {
        int c = hs[tid]; bs[tid] = c ? atomicAdd(&gcur_s[tid * GSTRIDE], c) : 0;
    }
    __syncthreads();
    for (int b = tid; b < NHALF; b += B1T) hd[b] = 0;
    for (int b = tid; b < NSB; b += B1T) hs[b] = 0;
    __syncthreads();

    // phase C: scatter into runs (dst_local(8b)<<17 | src; src_local as ushort)
#pragma unroll
    for (int i = 0; i < PEPT; ++i) {
        if (es[i] >= 0) {
            int s = es[i], d = ed[i];
            int kb = d >> 8;
            int pos = bd[kb] + atomicAdd(&hd[kb], 1);
            if (pos < CAPH) dreg[(size_t)kb * CAPH + pos] = ((d & 255) << 17) | s;
            int ks = s >> 9;
            int ps = bs[ks] + atomicAdd(&hs[ks], 1);
            if (ps < SCAP) sreg[(size_t)ks * SCAP + ps] = (unsigned short)(s & (SB - 1));
        }
    }
}

// ---------------- build2: shist || csr2 || gemm1, one 1024-thread dispatch ----------------
// Blocks [0, NSB): shist (src-degree histogram -> norm_s; bin Nn empty -> 1.0).
// Blocks [NSB, NSB+NHALF): csr2 per-half-bucket counting sort -> CSR + norm_d
// (hist/scatter by all 1024 threads; 256-bin scan by the first 4 waves).
// Rest: gemm1, 256 rows/block (16 waves x 16 rows), Hh = fp16(X@W1) UNSCALED
// (norm_s applied per-edge in gather); row Nn (sentinel) = 0.

__global__ __launch_bounds__(B2T)
void build2_kernel(const int* __restrict__ dreg, const int* __restrict__ gcur_d,
                   int* __restrict__ csr, int* __restrict__ starts,
                   int* __restrict__ ends, float* __restrict__ norm_d,
                   const float* __restrict__ Xv,
                   const _Float16* __restrict__ Wt, __half* __restrict__ Hh,
                   const unsigned short* __restrict__ sreg,
                   const int* __restrict__ gcur_s, float* __restrict__ norm_s,
                   int Nn) {
    __shared__ union SMem {
        int sh[SB];
        struct CS { int hist[256]; int cur[256]; int wsum[4]; int sorted[CAPH]; } c;
        _Float16 w[64 * (INF + 8)];
    } sm;
    const int tid = threadIdx.x;

    if (blockIdx.x < NSB) {
        // ---- shist: src-degree histogram per super-bucket -> norm_s ----
        const int sb = blockIdx.x;
        for (int i = tid; i < SB; i += B2T) sm.sh[i] = 0;
        __syncthreads();
        const int cnt = min(gcur_s[sb * GSTRIDE], SCAP);
        const unsigned short* base = sreg + (size_t)sb * SCAP;
        for (int i = tid; i < cnt; i += B2T) atomicAdd(&sm.sh[base[i]], 1);
        __syncthreads();
        for (int t = tid; t < SB; t += B2T) {
            int node = sb * SB + t;
            if (node <= Nn)     // node == Nn: empty bin -> 1.0 (sentinel scale)
                norm_s[node] = rsqrtf(fmaxf((float)sm.sh[t], 1.0f));
        }
        return;
    }

    if (blockIdx.x < NSB + NHALF) {
        // ---- csr2: WG j owns nodes [j*256, j*256+256) = dst bucket j ----
        const int j = blockIdx.x - NSB;
        const int cnt = min(gcur_d[j * GSTRIDE], CAPH);
        const int* reg = dreg + (size_t)j * CAPH;

        if (tid < 256) sm.c.hist[tid] = 0;
        __syncthreads();

        for (int i = tid; i < cnt; i += B2T)
            atomicAdd(&sm.c.hist[(reg[i] >> 17) & 255], 1);
        __syncthreads();

        // exclusive scan over 256 bins: first 4 waves, shfl_up + 4-word combine
        const int lane = tid & 63, wid = tid >> 6;
        int deg_n = 0, v = 0;
        if (tid < 256) {
            deg_n = sm.c.hist[tid];
            v = deg_n;
#pragma unroll
            for (int off = 1; off < 64; off <<= 1) {
                int u = __shfl_up(v, off, 64);
                if (lane >= off) v += u;
            }
            if (lane == 63) sm.c.wsum[wid] = v;
        }
        __syncthreads();
        if (tid < 256) {
            int wadd = 0;
#pragma unroll
            for (int q = 0; q < 3; ++q) wadd += (q < wid) ? sm.c.wsum[q] : 0;
            int st = v + wadd - deg_n;

            int node = j * 256 + tid;
            if (node < Nn) {
                int gs = j * CAPH + st;
                int dcl = min(deg_n, max(CAPH - st, 0));
                starts[node] = gs;
                ends[node]   = gs + dcl;
                norm_d[node] = rsqrtf(fmaxf((float)deg_n, 1.0f));
            }
            sm.c.cur[tid] = st;
        }
        __syncthreads();

        for (int i = tid; i < cnt; i += B2T) {
            int pe = reg[i];
            int pos = atomicAdd(&sm.c.cur[(pe >> 17) & 255], 1);
            if (pos < CAPH) sm.c.sorted[pos] = pe & SRCMASK;
        }
        __syncthreads();

        for (int i = tid; i < cnt; i += B2T) csr[(size_t)j * CAPH + i] = sm.c.sorted[i];
        return;
    }

    // ---- gemm1: block = 256 rows, 16 waves x 16; K=128 fp32 input ----
    constexpr int K = INF;
    constexpr int KP = K + 8;
    const int bid = blockIdx.x - NSB - NHALF;

    constexpr int NI4 = 64 * KP * 2 / 16;
    for (int i = tid; i < NI4; i += B2T)
        ((int4*)sm.w)[i] = ((const int4*)Wt)[i];
    __syncthreads();

    const int w = tid >> 6, lane = tid & 63;
    const int m16 = lane & 15, quad = lane >> 4;
    const int rowA = bid * 256 + w * 16 + m16;
    const int rowC = (rowA < Nn) ? rowA : (Nn - 1);

    floatx4 acc0 = {0.f, 0.f, 0.f, 0.f};
    floatx4 acc1 = acc0, acc2 = acc0, acc3 = acc0;

#pragma unroll
    for (int c = 0; c < K / 32; ++c) {
        const int k0 = c * 32 + quad * 8;
        const float* xrow = Xv + (size_t)rowC * K;
        float4 xa = *(const float4*)(xrow + k0);
        float4 xb = *(const float4*)(xrow + k0 + 4);
        half8 a;
        a[0] = (_Float16)xa.x; a[1] = (_Float16)xa.y;
        a[2] = (_Float16)xa.z; a[3] = (_Float16)xa.w;
        a[4] = (_Float16)xb.x; a[5] = (_Float16)xb.y;
        a[6] = (_Float16)xb.z; a[7] = (_Float16)xb.w;
        half8 b0 = *(const half8*)&sm.w[(0 * 16 + m16) * KP + k0];
        half8 b1 = *(const half8*)&sm.w[(1 * 16 + m16) * KP + k0];
        half8 b2 = *(const half8*)&sm.w[(2 * 16 + m16) * KP + k0];
        half8 b3 = *(const half8*)&sm.w[(3 * 16 + m16) * KP + k0];
        acc0 = __builtin_amdgcn_mfma_f32_16x16x32_f16(a, b0, acc0, 0, 0, 0);
        acc1 = __builtin_amdgcn_mfma_f32_16x16x32_f16(a, b1, acc1, 0, 0, 0);
        acc2 = __builtin_amdgcn_mfma_f32_16x16x32_f16(a, b2, acc2, 0, 0, 0);
        acc3 = __builtin_amdgcn_mfma_f32_16x16x32_f16(a, b3, acc3, 0, 0, 0);
    }

    const int rbase = bid * 256 + w * 16 + quad * 4;
    floatx4 accs[4] = {acc0, acc1, acc2, acc3};
#pragma unroll
    for (int i = 0; i < 4; ++i) {
        int grow = rbase + i;
        if (grow < Nn) {
            __half* o = Hh + (size_t)grow * 64 + m16;
#pragma unroll
            for (int t = 0; t < 4; ++t)
                o[16 * t] = (__half)accs[t][i];
        } else if (grow == Nn) {               // sentinel zero row for gather
            __half* o = Hh + (size_t)grow * 64 + m16;
#pragma unroll
            for (int t = 0; t < 4; ++t)
                o[16 * t] = (__half)0.f;
        }
    }
}

// ---------------- fused gatherL1 + gemm2: block = 64 nodes ----------------
// Phase 1: 2-node-per-wave pull gather with PER-EDGE norm_s scale
// (acc += ns[src] * h[src], fp32), epilogue writes relu(nd*acc + b1) fp16
// into LDS tile xt[64][72]. Phase 2: K=64 MFMA GEMM, A-frags from xt,
// output fp16(xt@W2) UNSCALED -> Xout (sentinel row Nn = 0).

__global__ void gather_gemm_kernel(const int* __restrict__ starts, const int* __restrict__ ends,
                                   const int* __restrict__ csr, const __half* __restrict__ Hh,
                                   const float* __restrict__ nd, const float* __restrict__ b,
                                   const float* __restrict__ ns, const _Float16* __restrict__ Wt,
                                   __half* __restrict__ Xout, int Nn) {
    constexpr int K = HID;
    constexpr int KP = K + 8;
    __shared__ _Float16 sWt[64 * KP];   // 9.2 KB
    __shared__ _Float16 xt[64 * KP];    // 9.2 KB x-tile

    const int tid = threadIdx.x;
    constexpr int NI4 = 64 * KP * 2 / 16;
    for (int i = tid; i < NI4; i += 256)
        ((int4*)sWt)[i] = ((const int4*)Wt)[i];
    // (barrier below covers sWt before phase 2 use)

    const int lane = tid & 63;
    const int half32 = (lane >> 5) & 1;         // node slot within wave
    const int l32 = lane & 31;                  // lane within half
    const int g = l32 >> 3;                     // edge slot group 0..3
    const int c = lane & 7;                     // 16B col chunk
    const int w = tid >> 6;
    const int m16 = lane & 15, quad = lane >> 4;

    // ---- phase 1: gather 16 nodes per wave (2 per iteration) ----
#pragma unroll 1
    for (int it = 0; it < 8; ++it) {
        const int nloc = w * 16 + it * 2 + half32;       // 0..63
        const int node = blockIdx.x * 64 + nloc;
        const int nodeC = (node < Nn) ? node : (Nn - 1);

        const int start = starts[nodeC];
        const int deg   = ends[nodeC] - start;
        const int dmax  = max(deg, __shfl_xor(deg, 32, 64));

        float acc[8] = {0.f, 0.f, 0.f, 0.f, 0.f, 0.f, 0.f, 0.f};

        for (int base = 0; base < dmax; base += 32) {
            int off = base + l32;
            int pe = (off < deg) ? csr[start + off] : Nn;  // sentinel: zero row
            int ecm = min(dmax - base, 32);
            int nkp = (ecm + 7) >> 3;

            for (int k = 0; k < nkp; ++k) {
                int j0 = g + 8 * k;
                int j1 = j0 + 4;
                int s0 = __shfl(pe, (lane & 32) + j0, 64);
                int s1 = __shfl(pe, (lane & 32) + j1, 64);
                float n0 = ns[s0], n1 = ns[s1];            // broadcast in group
                H8 v0, v1;
                v0.i4 = ((const int4*)(Hh + (size_t)s0 * 64))[c];
                v1.i4 = ((const int4*)(Hh + (size_t)s1 * 64))[c];
#pragma unroll
                for (int t = 0; t < 4; ++t) {
                    fma_mixs2(acc[2 * t], acc[2 * t + 1], v0.u[t], n0);
                    fma_mixs2(acc[2 * t], acc[2 * t + 1], v1.u[t], n1);
                }
            }
        }

#pragma unroll
        for (int m = 8; m <= 16; m <<= 1) {
#pragma unroll
            for (int k = 0; k < 8; ++k)
                acc[k] += __shfl_xor(acc[k], m, 64);
        }

        if (g == 0) {                           // 8 lanes per half -> LDS row
            float nm = nd[nodeC];
            float4 bb0 = ((const float4*)b)[2 * c];
            float4 bb1 = ((const float4*)b)[2 * c + 1];
            H8 o;
            o.h2[0] = __floats2half2_rn(fmaxf(fmaf(acc[0], nm, bb0.x), 0.f),
                                        fmaxf(fmaf(acc[1], nm, bb0.y), 0.f));
            o.h2[1] = __floats2half2_rn(fmaxf(fmaf(acc[2], nm, bb0.z), 0.f),
                                        fmaxf(fmaf(acc[3], nm, bb0.w), 0.f));
            o.h2[2] = __floats2half2_rn(fmaxf(fmaf(acc[4], nm, bb1.x), 0.f),
                                        fmaxf(fmaf(acc[5], nm, bb1.y), 0.f));
            o.h2[3] = __floats2half2_rn(fmaxf(fmaf(acc[6], nm, bb1.z), 0.f),
                                        fmaxf(fmaf(acc[7], nm, bb1.w), 0.f));
            *(int4*)(xt + nloc * KP + c * 8) = o.i4;
        }
    }
    __syncthreads();

    // ---- phase 2: gemm2, A from xt ----
    const int rowL = w * 16 + m16;

    floatx4 acc0 = {0.f, 0.f, 0.f, 0.f};
    floatx4 acc1 = acc0, acc2 = acc0, acc3 = acc0;

#pragma unroll
    for (int cc = 0; cc < K / 32; ++cc) {
        const int k0 = cc * 32 + quad * 8;
        half8 a = *(const half8*)&xt[rowL * KP + k0];
        half8 b0 = *(const half8*)&sWt[(0 * 16 + m16) * KP + k0];
        half8 b1 = *(const half8*)&sWt[(1 * 16 + m16) * KP + k0];
        half8 b2 = *(const half8*)&sWt[(2 * 16 + m16) * KP + k0];
        half8 b3 = *(const half8*)&sWt[(3 * 16 + m16) * KP + k0];
        acc0 = __builtin_amdgcn_mfma_f32_16x16x32_f16(a, b0, acc0, 0, 0, 0);
        acc1 = __builtin_amdgcn_mfma_f32_16x16x32_f16(a, b1, acc1, 0, 0, 0);
        acc2 = __builtin_amdgcn_mfma_f32_16x16x32_f16(a, b2, acc2, 0, 0, 0);
        acc3 = __builtin_amdgcn_mfma_f32_16x16x32_f16(a, b3, acc3, 0, 0, 0);
    }

    const int rbase = blockIdx.x * 64 + w * 16 + quad * 4;
    floatx4 accs[4] = {acc0, acc1, acc2, acc3};
#pragma unroll
    for (int i = 0; i < 4; ++i) {
        int grow = rbase + i;
        if (grow < Nn) {
            __half* o = Xout + (size_t)grow * 64 + m16;
#pragma unroll
            for (int t = 0; t < 4; ++t)
                o[16 * t] = (__half)accs[t][i];
        } else if (grow == Nn) {               // sentinel zero row for gatherL2
            __half* o = Xout + (size_t)grow * 64 + m16;
#pragma unroll
            for (int t = 0; t < 4; ++t)
                o[16 * t] = (__half)0.f;
        }
    }
}

// ---------------- pull gather L2 + fused projection/softmax ----------------
// Per-edge norm_s scale; sentinel tail slots. Epilogue: x@Wp + bp + softmax
// in-register (labels 2/g-group, LDS Wp transposed pad-65, butterflies over
// c then g; c==0 lanes store float2).

__global__ void gather_proj_kernel(const int* __restrict__ starts, const int* __restrict__ ends,
                                   const int* __restrict__ csr, const __half* __restrict__ Hh,
                                   const float* __restrict__ nd, const float* __restrict__ b,
                                   const float* __restrict__ ns,
                                   const float* __restrict__ Wp, const float* __restrict__ bp,
                                   float* __restrict__ out, int Nn) {
    __shared__ float sW[NLAB * 65];     // [label][feat], pad 65
    __shared__ float sb_[NLAB];
    const int tid = threadIdx.x;

    for (int i = tid; i < 64 * NLAB; i += 256) {
        int k = i >> 3, l = i & 7;
        sW[l * 65 + k] = Wp[i];         // transpose: Wp is [feat][label]
    }
    if (tid < NLAB) sb_[tid] = bp[tid];
    __syncthreads();

    const int lane = tid & 63;
    const int half32 = (lane >> 5) & 1;
    const int l32 = lane & 31;
    const int g = l32 >> 3;
    const int c = lane & 7;

    int node = blockIdx.x * 8 + ((tid >> 6) << 1) + half32;
    const bool valid = node < Nn;
    const int nodeC = valid ? node : (Nn - 1);

    const int start = starts[nodeC];
    const int deg   = ends[nodeC] - start;
    const int dmax  = max(deg, __shfl_xor(deg, 32, 64));

    float acc[8] = {0.f, 0.f, 0.f, 0.f, 0.f, 0.f, 0.f, 0.f};

    for (int base = 0; base < dmax; base += 32) {
        int off = base + l32;
        int pe = (off < deg) ? csr[start + off] : Nn;  // sentinel: zero row
        int ecm = min(dmax - base, 32);
        int nkp = (ecm + 7) >> 3;

        for (int k = 0; k < nkp; ++k) {
            int j0 = g + 8 * k;
            int j1 = j0 + 4;
            int s0 = __shfl(pe, (lane & 32) + j0, 64);
            int s1 = __shfl(pe, (lane & 32) + j1, 64);
            float n0 = ns[s0], n1 = ns[s1];            // broadcast in group
            H8 v0, v1;
            v0.i4 = ((const int4*)(Hh + (size_t)s0 * 64))[c];
            v1.i4 = ((const int4*)(Hh + (size_t)s1 * 64))[c];
#pragma unroll
            for (int t = 0; t < 4; ++t) {
                fma_mixs2(acc[2 * t], acc[2 * t + 1], v0.u[t], n0);
                fma_mixs2(acc[2 * t], acc[2 * t + 1], v1.u[t], n1);
            }
        }
    }

#pragma unroll
    for (int m = 8; m <= 16; m <<= 1) {
#pragma unroll
        for (int k = 0; k < 8; ++k)
            acc[k] += __shfl_xor(acc[k], m, 64);
    }

    // x row (fp32, un-rounded): feats 8c..8c+7, replicated across g
    float nm = nd[nodeC];
    float4 b0 = ((const float4*)b)[2 * c];
    float4 b1 = ((const float4*)b)[2 * c + 1];
    float xv[8];
    xv[0] = fmaxf(fmaf(acc[0], nm, b0.x), 0.f);
    xv[1] = fmaxf(fmaf(acc[1], nm, b0.y), 0.f);
    xv[2] = fmaxf(fmaf(acc[2], nm, b0.z), 0.f);
    xv[3] = fmaxf(fmaf(acc[3], nm, b0.w), 0.f);
    xv[4] = fmaxf(fmaf(acc[4], nm, b1.x), 0.f);
    xv[5] = fmaxf(fmaf(acc[5], nm, b1.y), 0.f);
    xv[6] = fmaxf(fmaf(acc[6], nm, b1.z), 0.f);
    xv[7] = fmaxf(fmaf(acc[7], nm, b1.w), 0.f);

    const int l0 = 2 * g, l1 = l0 + 1;
    float p0 = 0.f, p1 = 0.f;
#pragma unroll
    for (int j = 0; j < 8; ++j) {
        p0 = fmaf(xv[j], sW[l0 * 65 + 8 * c + j], p0);
        p1 = fmaf(xv[j], sW[l1 * 65 + 8 * c + j], p1);
    }
    p0 += __shfl_xor(p0, 1, 64); p1 += __shfl_xor(p1, 1, 64);
    p0 += __shfl_xor(p0, 2, 64); p1 += __shfl_xor(p1, 2, 64);
    p0 += __shfl_xor(p0, 4, 64); p1 += __shfl_xor(p1, 4, 64);
    p0 += sb_[l0];
    p1 += sb_[l1];
    float mx = fmaxf(p0, p1);
    mx = fmaxf(mx, __shfl_xor(mx, 8, 64));
    mx = fmaxf(mx, __shfl_xor(mx, 16, 64));
    float e0 = __expf(p0 - mx), e1 = __expf(p1 - mx);
    float s2 = e0 + e1;
    s2 += __shfl_xor(s2, 8, 64);
    s2 += __shfl_xor(s2, 16, 64);
    float inv = 1.0f / s2;
    if (c == 0 && valid) {
        float2 o = {e0 * inv, e1 * inv};
        *(float2*)(out + (size_t)node * NLAB + l0) = o;
    }
}

// ---------------- launch ----------------

extern "C" void kernel_launch(void* const* d_in, const int* in_sizes, int n_in,
                              void* d_out, int out_size, void* d_ws, size_t ws_size,
                              hipStream_t stream) {
    const float* features = (const float*)d_in[0];
    const int*   edge_src = (const int*)d_in[1];
    const int*   edge_dst = (const int*)d_in[2];
    const float* W1 = (const float*)d_in[4];
    const float* b1 = (const float*)d_in[5];
    const float* W2 = (const float*)d_in[6];
    const float* b2 = (const float*)d_in[7];
    const float* Wp = (const float*)d_in[8];
    const float* bp = (const float*)d_in[9];
    float* out = (float*)d_out;

    const int N = NODES;
    const int E = in_sizes[1];

    // ---- workspace layout (~35 MB) ----
    // h and x both have N+64 rows (row N = sentinel zero row). norm_s has
    // N+16 entries (entry N = 1.0 sentinel scale). dreg/sreg alias x (dead
    // until gather_gemm writes x): shist/csr2 consume them strictly before.
    char* p = (char*)d_ws;
    int*   csr    = (int*)p;            p += sizeof(int) * (size_t)NHALF * CAPH;  // 7.2 MB
    int*   starts = (int*)p;            p += sizeof(int) * N;
    int*   ends   = (int*)p;            p += sizeof(int) * N;
    float* norm_s = (float*)p;          p += sizeof(float) * (N + 16);
    float* norm_d = (float*)p;          p += sizeof(float) * N;
    int*   gcur_d = (int*)p;            p += sizeof(int) * NHALF * GSTRIDE;  // zeroed
    int*   gcur_s = (int*)p;            p += sizeof(int) * NSB * GSTRIDE;    // zeroed
    p = (char*)(((size_t)p + 255) & ~(size_t)255);
    _Float16* wt1 = (_Float16*)p;       p += sizeof(_Float16) * 64 * (INF + 8);
    _Float16* wt2 = (_Float16*)p;       p += sizeof(_Float16) * 64 * (HID + 8);
    p = (char*)(((size_t)p + 255) & ~(size_t)255);
    __half* h     = (__half*)p;         p += sizeof(__half) * ((size_t)N + 64) * 64; // + sentinel
    p = (char*)(((size_t)p + 255) & ~(size_t)255);
    __half* x     = (__half*)p;         p += sizeof(__half) * ((size_t)N + 64) * 64; // + sentinel
    // aliases inside x (dead before gather_gemm writes x):
    int*            dreg = (int*)x;                                              // 7.19 MB
    unsigned short* sreg = (unsigned short*)((char*)x + sizeof(int) * (size_t)NHALF * CAPH); // 3.5 MB

    hipMemsetAsync(gcur_d, 0, sizeof(int) * (NHALF + NSB) * GSTRIDE, stream);

    // ---- build: [partition || wcvt] -> [shist || CSR || gemm1] ----
    const int partWGs = (E + PCHUNK - 1) / PCHUNK;
    build1_kernel<<<partWGs + WCVT_WGS, B1T, 0, stream>>>(edge_src, edge_dst,
                                                          gcur_d, gcur_s, dreg, sreg,
                                                          E, partWGs, W1, W2, wt1, wt2);
    build2_kernel<<<NSB + NHALF + (N + 255) / 256, B2T, 0, stream>>>(dreg, gcur_d, csr,
                                                                     starts, ends, norm_d,
                                                                     features, wt1, h,
                                                                     sreg, gcur_s, norm_s, N);

    // ---- fused: gatherL1 (per-edge ns scale, h -> LDS tile) + gemm2 (-> x) ----
    gather_gemm_kernel<<<(N + 63) / 64, 256, 0, stream>>>(starts, ends, csr, h, norm_d,
                                                          b1, norm_s, wt2, x, N);

    // ---- gatherL2 (per-edge ns scale) + projection + softmax ----
    gather_proj_kernel<<<(N + 7) / 8, 256, 0, stream>>>(starts, ends, csr, x, norm_d,
                                                        b2, norm_s, Wp, bp, out, N);
}